// Round 4
// baseline (1109.427 us; speedup 1.0000x reference)
//
#include <hip/hip_runtime.h>
#include <hip/hip_bf16.h>
#include <math.h>

#define S_    2048
#define HID_  4096
#define HQ_   32
#define HKV_  8
#define D_    128
#define G_    4
#define OBS_  128
#define W_    32
#define NKV_  1024
#define NQ_   4096
#define KLD_  2048
#define SCALE_ 0.08838834764831845f
#define THR_IDX_ 89
#define NC_   16128

typedef __attribute__((ext_vector_type(4))) float f32x4;
typedef __attribute__((ext_vector_type(8))) short s16x8;
typedef __attribute__((ext_vector_type(8))) unsigned short u16x8;
typedef __attribute__((ext_vector_type(4))) unsigned short u16x4;
typedef unsigned short ushort_t;

__device__ __forceinline__ unsigned short f2bf(float x) {
  union { float f; unsigned u; } v; v.f = x;
  unsigned r = v.u + 0x7FFFu + ((v.u >> 16) & 1u);
  return (unsigned short)(r >> 16);
}
__device__ __forceinline__ float bf2f(unsigned short b) {
  union { unsigned u; float f; } v; v.u = ((unsigned)b) << 16;
  return v.f;
}
__device__ __forceinline__ void gload_lds16(const void* g, void* l) {
  __builtin_amdgcn_global_load_lds((const __attribute__((address_space(1))) unsigned int*)g,
                                   (__attribute__((address_space(3))) unsigned int*)l, 16, 0, 0);
}

// ---------------- split fp32 -> 3 bf16 terms ----------------
__global__ __launch_bounds__(256) void split3_kernel(const float* __restrict__ src,
                                                     ushort_t* __restrict__ d0,
                                                     ushort_t* __restrict__ d1,
                                                     ushort_t* __restrict__ d2, int n4) {
  int idx = blockIdx.x * 256 + threadIdx.x;
  if (idx >= n4) return;
  float4 v = ((const float4*)src)[idx];
  u16x4 o0, o1, o2;
  float xs[4] = {v.x, v.y, v.z, v.w};
#pragma unroll
  for (int e = 0; e < 4; ++e) {
    float x = xs[e];
    unsigned short b0 = f2bf(x);
    float r = x - bf2f(b0);
    unsigned short b1 = f2bf(r);
    float r2 = r - bf2f(b1);
    unsigned short b2 = f2bf(r2);
    o0[e] = b0; o1[e] = b1; o2[e] = b2;
  }
  *(u16x4*)(d0 + (size_t)idx * 4) = o0;
  *(u16x4*)(d1 + (size_t)idx * 4) = o1;
  *(u16x4*)(d2 + (size_t)idx * 4) = o2;
}

// ---------------- split + transpose weights ----------------
__global__ __launch_bounds__(256) void splitT_kernel(const float* __restrict__ src, int N,
                                                     ushort_t* __restrict__ t0,
                                                     ushort_t* __restrict__ t1,
                                                     ushort_t* __restrict__ t2) {
  __shared__ float tile[64][65];
  const int t = threadIdx.x;
  const int n0 = blockIdx.x * 64, k0 = blockIdx.y * 64;
#pragma unroll
  for (int i = 0; i < 16; ++i) {
    int idx = i * 256 + t;
    int r = idx >> 6, c = idx & 63;
    tile[r][c] = src[(size_t)(k0 + r) * N + n0 + c];
  }
  __syncthreads();
#pragma unroll
  for (int i = 0; i < 16; ++i) {
    int idx = i * 256 + t;
    int n = idx >> 6, kk = idx & 63;
    float x = tile[kk][n];
    unsigned short b0 = f2bf(x);
    size_t o = (size_t)(n0 + n) * HID_ + k0 + kk;
    t0[o] = b0;
    if (t1) {
      float r = x - bf2f(b0);
      unsigned short b1 = f2bf(r);
      t1[o] = b1;
      float r2 = r - bf2f(b1);
      t2[o] = f2bf(r2);
    }
  }
}

// ---------------- unified bf16 MFMA GEMM ----------------
template<int MODE>
__global__ __launch_bounds__(256) void gemm_bt(const ushort_t* __restrict__ A0,
                                               const ushort_t* __restrict__ A1,
                                               const ushort_t* __restrict__ B0,
                                               const ushort_t* __restrict__ B1,
                                               float* __restrict__ C,
                                               int M, int N, int K) {
  constexpr int NT = (MODE == 0) ? 2 : 4;
  __shared__ ushort_t lds[NT * 128 * 64];
  const int t = threadIdx.x;
  const int wave = t >> 6, lane = t & 63;
  const int lc = lane & 15, lg = lane >> 4;
  const int bm = blockIdx.y, bn = blockIdx.x;
  const int wm = wave >> 1, wn = wave & 1;
  const int srow = t >> 3;
  const int schunk = t & 7;

  f32x4 acc[4][4];
#pragma unroll
  for (int fi = 0; fi < 4; ++fi)
#pragma unroll
    for (int fj = 0; fj < 4; ++fj) acc[fi][fj] = 0.f;

  for (int kb = 0; kb < K / 64; ++kb) {
    __syncthreads();
#pragma unroll
    for (int tid = 0; tid < NT; ++tid) {
      const ushort_t* src = (tid == 0) ? A0 : (tid == 1) ? B0 : (tid == 2) ? A1 : B1;
      const int rb = (tid == 0 || tid == 2) ? bm : bn;
#pragma unroll
      for (int g = 0; g < 4; ++g) {
        int row = g * 32 + srow;
        int sw = schunk ^ (row & 7);
        const ushort_t* gp = src + (size_t)(rb * 128 + row) * K + kb * 64 + sw * 8;
        ushort_t* lp = lds + tid * 8192 + g * 2048 + wave * 512;
        gload_lds16(gp, lp);
      }
    }
    __syncthreads();
#pragma unroll
    for (int ks = 0; ks < 2; ++ks) {
      s16x8 a0f[4], b0f[4], a1f[4], b1f[4];
#pragma unroll
      for (int f = 0; f < 4; ++f) {
        int ra = wm * 64 + f * 16 + lc;
        int ca = ((ks * 4 + lg) ^ (ra & 7)) * 8;
        a0f[f] = *(const s16x8*)(lds + 0 * 8192 + ra * 64 + ca);
        int rb2 = wn * 64 + f * 16 + lc;
        int cb = ((ks * 4 + lg) ^ (rb2 & 7)) * 8;
        b0f[f] = *(const s16x8*)(lds + 1 * 8192 + rb2 * 64 + cb);
        if constexpr (MODE >= 1) {
          a1f[f] = *(const s16x8*)(lds + 2 * 8192 + ra * 64 + ca);
          b1f[f] = *(const s16x8*)(lds + 3 * 8192 + rb2 * 64 + cb);
        }
      }
#pragma unroll
      for (int fi = 0; fi < 4; ++fi)
#pragma unroll
        for (int fj = 0; fj < 4; ++fj) {
          if constexpr (MODE == 0) {
            acc[fi][fj] = __builtin_amdgcn_mfma_f32_16x16x32_bf16(a0f[fi], b0f[fj], acc[fi][fj], 0, 0, 0);
          } else if constexpr (MODE == 1) {
            acc[fi][fj] = __builtin_amdgcn_mfma_f32_16x16x32_bf16(a0f[fi], b0f[fj], acc[fi][fj], 0, 0, 0);
            acc[fi][fj] = __builtin_amdgcn_mfma_f32_16x16x32_bf16(a0f[fi], b1f[fj], acc[fi][fj], 0, 0, 0);
            acc[fi][fj] = __builtin_amdgcn_mfma_f32_16x16x32_bf16(a1f[fi], b0f[fj], acc[fi][fj], 0, 0, 0);
            acc[fi][fj] = __builtin_amdgcn_mfma_f32_16x16x32_bf16(a1f[fi], b1f[fj], acc[fi][fj], 0, 0, 0);
          } else {
            acc[fi][fj] = __builtin_amdgcn_mfma_f32_16x16x32_bf16(a0f[fi], b1f[fj], acc[fi][fj], 0, 0, 0);
            acc[fi][fj] = __builtin_amdgcn_mfma_f32_16x16x32_bf16(a1f[fi], b0f[fj], acc[fi][fj], 0, 0, 0);
          }
        }
    }
  }
#pragma unroll
  for (int fi = 0; fi < 4; ++fi)
#pragma unroll
    for (int fj = 0; fj < 4; ++fj)
#pragma unroll
      for (int r = 0; r < 4; ++r) {
        size_t o = (size_t)(bm * 128 + wm * 64 + fi * 16 + lg * 4 + r) * N +
                   bn * 128 + wn * 64 + fj * 16 + lc;
        if constexpr (MODE == 2) C[o] += acc[fi][fj][r];
        else C[o] = acc[fi][fj][r];
      }
}

// ---------------- z-batched variant for obs GEMM (per-kv-head) ----------------
template<int MODE>
__global__ __launch_bounds__(256) void gemm_btz(const ushort_t* __restrict__ A0g,
                                                const ushort_t* __restrict__ A1g,
                                                const ushort_t* __restrict__ B0g,
                                                const ushort_t* __restrict__ B1g,
                                                float* __restrict__ Cg,
                                                int M, int N, int K) {
  __shared__ ushort_t lds[4 * 128 * 64];
  const int z = blockIdx.z;
  const ushort_t* A0 = A0g + (size_t)z * M * K;
  const ushort_t* A1 = A1g + (size_t)z * M * K;
  const ushort_t* B0 = B0g + (size_t)z * N * K;
  const ushort_t* B1 = B1g + (size_t)z * N * K;
  float* C = Cg + (size_t)z * M * N;
  const int t = threadIdx.x;
  const int wave = t >> 6, lane = t & 63;
  const int lc = lane & 15, lg = lane >> 4;
  const int bm = blockIdx.y, bn = blockIdx.x;
  const int wm = wave >> 1, wn = wave & 1;
  const int srow = t >> 3;
  const int schunk = t & 7;

  f32x4 acc[4][4];
#pragma unroll
  for (int fi = 0; fi < 4; ++fi)
#pragma unroll
    for (int fj = 0; fj < 4; ++fj) acc[fi][fj] = 0.f;

  for (int kb = 0; kb < K / 64; ++kb) {
    __syncthreads();
#pragma unroll
    for (int tid = 0; tid < 4; ++tid) {
      const ushort_t* src = (tid == 0) ? A0 : (tid == 1) ? B0 : (tid == 2) ? A1 : B1;
      const int rb = (tid == 0 || tid == 2) ? bm : bn;
#pragma unroll
      for (int g = 0; g < 4; ++g) {
        int row = g * 32 + srow;
        int sw = schunk ^ (row & 7);
        const ushort_t* gp = src + (size_t)(rb * 128 + row) * K + kb * 64 + sw * 8;
        ushort_t* lp = lds + tid * 8192 + g * 2048 + wave * 512;
        gload_lds16(gp, lp);
      }
    }
    __syncthreads();
#pragma unroll
    for (int ks = 0; ks < 2; ++ks) {
      s16x8 a0f[4], b0f[4], a1f[4], b1f[4];
#pragma unroll
      for (int f = 0; f < 4; ++f) {
        int ra = wm * 64 + f * 16 + lc;
        int ca = ((ks * 4 + lg) ^ (ra & 7)) * 8;
        a0f[f] = *(const s16x8*)(lds + 0 * 8192 + ra * 64 + ca);
        int rb2 = wn * 64 + f * 16 + lc;
        int cb = ((ks * 4 + lg) ^ (rb2 & 7)) * 8;
        b0f[f] = *(const s16x8*)(lds + 1 * 8192 + rb2 * 64 + cb);
        a1f[f] = *(const s16x8*)(lds + 2 * 8192 + ra * 64 + ca);
        b1f[f] = *(const s16x8*)(lds + 3 * 8192 + rb2 * 64 + cb);
      }
#pragma unroll
      for (int fi = 0; fi < 4; ++fi)
#pragma unroll
        for (int fj = 0; fj < 4; ++fj) {
          if constexpr (MODE == 1) {
            acc[fi][fj] = __builtin_amdgcn_mfma_f32_16x16x32_bf16(a0f[fi], b0f[fj], acc[fi][fj], 0, 0, 0);
            acc[fi][fj] = __builtin_amdgcn_mfma_f32_16x16x32_bf16(a0f[fi], b1f[fj], acc[fi][fj], 0, 0, 0);
            acc[fi][fj] = __builtin_amdgcn_mfma_f32_16x16x32_bf16(a1f[fi], b0f[fj], acc[fi][fj], 0, 0, 0);
            acc[fi][fj] = __builtin_amdgcn_mfma_f32_16x16x32_bf16(a1f[fi], b1f[fj], acc[fi][fj], 0, 0, 0);
          } else {
            acc[fi][fj] = __builtin_amdgcn_mfma_f32_16x16x32_bf16(a0f[fi], b1f[fj], acc[fi][fj], 0, 0, 0);
            acc[fi][fj] = __builtin_amdgcn_mfma_f32_16x16x32_bf16(a1f[fi], b0f[fj], acc[fi][fj], 0, 0, 0);
          }
        }
    }
  }
#pragma unroll
  for (int fi = 0; fi < 4; ++fi)
#pragma unroll
    for (int fj = 0; fj < 4; ++fj)
#pragma unroll
      for (int r = 0; r < 4; ++r) {
        size_t o = (size_t)(bm * 128 + wm * 64 + fi * 16 + lg * 4 + r) * N +
                   bn * 128 + wn * 64 + fj * 16 + lc;
        if constexpr (MODE == 2) C[o] += acc[fi][fj][r];
        else C[o] = acc[fi][fj][r];
      }
}

// ---------------- fp32 obs-Q GEMM (exact fp32 decision path) ----------------
__global__ __launch_bounds__(256) void gemm_obsq(const float* __restrict__ A,
                                                 const float* __restrict__ Bw,
                                                 float* __restrict__ Cp) {
  __shared__ float a_t[16][136];
  __shared__ float b_t[16][136];
  const int t = threadIdx.x, tx = t & 15, ty = t >> 4;
  const int bn = blockIdx.x, z = blockIdx.z;
  float acc[8][8];
#pragma unroll
  for (int i = 0; i < 8; i++)
#pragma unroll
    for (int j = 0; j < 8; j++) acc[i][j] = 0.f;
  for (int kb = z * 16; kb < z * 16 + 16; ++kb) {
    __syncthreads();
#pragma unroll
    for (int u = 0; u < 2; ++u) {
      int idx = t * 2 + u;
      int r = idx >> 2, c4 = idx & 3;
      float4 va = *(const float4*)(A + (size_t)r * HID_ + kb * 16 + c4 * 4);
      a_t[c4 * 4 + 0][r] = va.x; a_t[c4 * 4 + 1][r] = va.y;
      a_t[c4 * 4 + 2][r] = va.z; a_t[c4 * 4 + 3][r] = va.w;
      int rb = idx >> 5, cb = idx & 31;
      float4 vb = *(const float4*)(Bw + (size_t)(kb * 16 + rb) * NQ_ + bn * 128 + cb * 4);
      *(float4*)&b_t[rb][cb * 4] = vb;
    }
    __syncthreads();
#pragma unroll
    for (int kk = 0; kk < 16; ++kk) {
      float a0[8], b0[8];
      *(float4*)&a0[0] = *(const float4*)&a_t[kk][ty * 8];
      *(float4*)&a0[4] = *(const float4*)&a_t[kk][ty * 8 + 4];
      *(float4*)&b0[0] = *(const float4*)&b_t[kk][tx * 8];
      *(float4*)&b0[4] = *(const float4*)&b_t[kk][tx * 8 + 4];
#pragma unroll
      for (int i = 0; i < 8; i++)
#pragma unroll
        for (int j = 0; j < 8; j++) acc[i][j] = fmaf(a0[i], b0[j], acc[i][j]);
    }
  }
  float* cp0 = Cp + (size_t)z * 128 * NQ_;
#pragma unroll
  for (int i = 0; i < 8; i++) {
    float* cp = cp0 + (size_t)(ty * 8 + i) * NQ_ + bn * 128 + tx * 8;
    *(float4*)cp = *(float4*)&acc[i][0];
    *(float4*)(cp + 4) = *(float4*)&acc[i][4];
  }
}

__global__ void reduce16_kernel(const float* __restrict__ Cp, float* __restrict__ out, int n) {
  int idx = blockIdx.x * 256 + threadIdx.x;
  if (idx >= n) return;
  float s = 0.f;
#pragma unroll
  for (int z = 0; z < 16; ++z) s += Cp[(size_t)z * n + idx];
  out[idx] = s;
}

// ---------------- inv_freq ----------------
__global__ void freq_kernel(float* __restrict__ invf) {
  int j = threadIdx.x;
  if (j < 64) invf[j] = (float)(1.0 / pow(500000.0, (double)j / 64.0));
}

// ---------------- RoPE ----------------
__global__ void rope_kernel(float* __restrict__ X, ushort_t* __restrict__ Xb,
                            const float* __restrict__ invf, int H, int ld, int pos0, int total) {
  int idx = blockIdx.x * 256 + threadIdx.x;
  if (idx >= total) return;
  int j = idx & 63;
  int h = (idx >> 6) % H;
  int s = idx / (64 * H);
  float ang = (float)(pos0 + s) * invf[j];
  float sn, cs;
  sincosf(ang, &sn, &cs);
  size_t base = (size_t)s * ld + h * D_ + j;
  float x1 = X[base], x2 = X[base + 64];
  float o1 = x1 * cs - x2 * sn;
  float o2 = x2 * cs + x1 * sn;
  X[base] = o1; X[base + 64] = o2;
  if (Xb) { Xb[base] = f2bf(o1); Xb[base + 64] = f2bf(o2); }
}

// ---------------- obs-Q 3-split into [hk][g*128+i][d] ----------------
__global__ __launch_bounds__(256) void splitq_obs(const float* __restrict__ qobs,
                                                  ushort_t* __restrict__ q0,
                                                  ushort_t* __restrict__ q1,
                                                  ushort_t* __restrict__ q2) {
  int idx = blockIdx.x * 256 + threadIdx.x;   // 131072 total
  if (idx >= OBS_ * NQ_ / 4) return;
  int idx4 = idx * 4;
  int i = idx4 >> 12;
  int col = idx4 & 4095;
  int hq = col >> 7, d = col & 127;
  int hk = hq >> 2, g = hq & 3;
  float4 v = *(const float4*)(qobs + (size_t)i * NQ_ + col);
  size_t o = (size_t)hk * 65536 + (size_t)(g * 128 + i) * 128 + d;
  float xs[4] = {v.x, v.y, v.z, v.w};
  u16x4 o0, o1, o2;
#pragma unroll
  for (int e = 0; e < 4; ++e) {
    float x = xs[e];
    unsigned short b0 = f2bf(x);
    float r = x - bf2f(b0);
    unsigned short b1 = f2bf(r);
    o0[e] = b0; o1[e] = b1; o2[e] = f2bf(r - bf2f(b1));
  }
  *(u16x4*)(q0 + o) = o0;
  *(u16x4*)(q1 + o) = o1;
  *(u16x4*)(q2 + o) = o2;
}

// ---------------- K 3-split into [hk][j][d] ----------------
__global__ __launch_bounds__(256) void splitk_obs(const float* __restrict__ kvf,
                                                  ushort_t* __restrict__ k0,
                                                  ushort_t* __restrict__ k1,
                                                  ushort_t* __restrict__ k2) {
  int idx = blockIdx.x * 256 + threadIdx.x;   // 524288 total
  if (idx >= S_ * NKV_ / 4) return;
  int idx4 = idx * 4;
  int j = idx4 >> 10;
  int col = idx4 & 1023;
  int hk = col >> 7, d = col & 127;
  float4 v = *(const float4*)(kvf + (size_t)j * KLD_ + col);
  size_t o = (size_t)hk * 262144 + ((size_t)j << 7) + d;
  float xs[4] = {v.x, v.y, v.z, v.w};
  u16x4 o0, o1, o2;
#pragma unroll
  for (int e = 0; e < 4; ++e) {
    float x = xs[e];
    unsigned short b0 = f2bf(x);
    float r = x - bf2f(b0);
    unsigned short b1 = f2bf(r);
    o0[e] = b0; o1[e] = b1; o2[e] = f2bf(r - bf2f(b1));
  }
  *(u16x4*)(k0 + o) = o0;
  *(u16x4*)(k1 + o) = o1;
  *(u16x4*)(k2 + o) = o2;
}

// ---------------- per-row max + inv-denominator (causal) ----------------
__global__ __launch_bounds__(256) void rowstat_kernel(const float* __restrict__ s,
                                                      float* __restrict__ mx,
                                                      float* __restrict__ dinv) {
  const int row = blockIdx.x * 4 + (threadIdx.x >> 6);   // 0..4095
  const int lane = threadIdx.x & 63;
  const int i = row & 127;
  const int jmax = S_ - OBS_ + i;
  const float* sp = s + (size_t)row * S_;
  float vals[32];
  float m = -INFINITY;
#pragma unroll
  for (int c = 0; c < 8; ++c) {
    int j0 = c * 256 + lane * 4;
    float4 v = *(const float4*)(sp + j0);
    float e0 = (j0 + 0 <= jmax) ? v.x * SCALE_ : -INFINITY;
    float e1 = (j0 + 1 <= jmax) ? v.y * SCALE_ : -INFINITY;
    float e2 = (j0 + 2 <= jmax) ? v.z * SCALE_ : -INFINITY;
    float e3 = (j0 + 3 <= jmax) ? v.w * SCALE_ : -INFINITY;
    vals[c * 4 + 0] = e0; vals[c * 4 + 1] = e1; vals[c * 4 + 2] = e2; vals[c * 4 + 3] = e3;
    m = fmaxf(m, fmaxf(fmaxf(e0, e1), fmaxf(e2, e3)));
  }
#pragma unroll
  for (int off = 1; off < 64; off <<= 1) m = fmaxf(m, __shfl_xor(m, off, 64));
  float ssum = 0.f;
#pragma unroll
  for (int c = 0; c < 32; ++c) ssum += expf(vals[c] - m);
#pragma unroll
  for (int off = 1; off < 64; off <<= 1) ssum += __shfl_xor(ssum, off, 64);
  if (lane == 0) { mx[row] = m; dinv[row] = 1.0f / ssum; }
}

// ---------------- column-sum of softmax -> imp (deterministic) ----------------
__global__ __launch_bounds__(256) void colsum_kernel(const float* __restrict__ s,
                                                     const float* __restrict__ mx,
                                                     const float* __restrict__ dinv,
                                                     float* __restrict__ imp) {
  __shared__ float mxl[512], dvl[512];
  const int hk = blockIdx.y, jt = blockIdx.x, t = threadIdx.x;
  for (int r = t; r < 512; r += 256) {
    mxl[r] = mx[hk * 512 + r];
    dvl[r] = dinv[hk * 512 + r];
  }
  __syncthreads();
  const int j = jt * 256 + t;
  const float* sp = s + (size_t)hk * 512 * S_ + j;
  float acc = 0.f;
  for (int r = 0; r < 512; ++r) {
    int i = r & 127;
    if (j <= S_ - OBS_ + i)
      acc += expf(sp[(size_t)r * S_] * SCALE_ - mxl[r]) * dvl[r];
  }
  float cnt = (float)min(OBS_, S_ - j);
  imp[hk * S_ + j] = acc * 0.25f / cnt;
}

// ---------------- radix select ----------------
__global__ void radix_init(unsigned* prefix, unsigned* kneed) {
  if (threadIdx.x == 0) {
    prefix[0] = prefix[1] = prefix[2] = prefix[3] = 0u;
    kneed[0] = 3225u; kneed[1] = 3226u; kneed[2] = 15320u; kneed[3] = 15321u;
  }
}
__global__ __launch_bounds__(256) void radix_hist(const float* __restrict__ imp,
                                                  const unsigned* __restrict__ prefix,
                                                  int pass, unsigned* __restrict__ hist) {
  __shared__ unsigned lh[1024];
  int t = threadIdx.x;
  for (int i = t; i < 1024; i += 256) lh[i] = 0u;
  __syncthreads();
  int idx = blockIdx.x * 256 + t;
  if (idx < NC_) {
    int h = idx / (S_ - W_), j = idx - h * (S_ - W_);
    union { float f; unsigned u; } cv; cv.f = imp[h * S_ + j];
    unsigned u = cv.u;
    int shift = 24 - pass * 8;
#pragma unroll
    for (int t4 = 0; t4 < 4; ++t4) {
      bool m = (pass == 0) || ((u >> (shift + 8)) == (prefix[t4] >> (shift + 8)));
      if (m) atomicAdd(&lh[t4 * 256 + ((u >> shift) & 255u)], 1u);
    }
  }
  __syncthreads();
  for (int i = t; i < 1024; i += 256) if (lh[i]) atomicAdd(&hist[i], lh[i]);
}
__global__ void radix_scan(const unsigned* __restrict__ hist, unsigned* prefix,
                           unsigned* kneed, int pass, float* thr) {
  int t = threadIdx.x;
  __shared__ unsigned selbits[4];
  if (t < 4) {
    unsigned need = kneed[t];
    unsigned cum = 0;
    int shift = 24 - pass * 8;
    unsigned pfx = prefix[t];
    for (int d = 0; d < 256; ++d) {
      unsigned c = hist[t * 256 + d];
      if (cum + c > need) { pfx |= ((unsigned)d) << shift; kneed[t] = need - cum; break; }
      cum += c;
    }
    prefix[t] = pfx;
    selbits[t] = pfx;
  }
  __syncthreads();
  if (pass == 3 && t == 0) {
    union { unsigned u; float f; } c0, c1, c2, c3;
    c0.u = selbits[0]; c1.u = selbits[1]; c2.u = selbits[2]; c3.u = selbits[3];
    double fl = 0.2 * (double)(NC_ - 1) - 3225.0;
    double fh = 0.95 * (double)(NC_ - 1) - 15320.0;
    thr[0] = (float)((double)c2.f + ((double)c3.f - (double)c2.f) * fh);
    thr[1] = (float)((double)c0.f + ((double)c1.f - (double)c0.f) * fl);
  }
}

// ---------------- sparsify ----------------
__global__ __launch_bounds__(128) void sparsify_kernel(const float* __restrict__ kv,
                                                       const float* __restrict__ imp,
                                                       const float* __restrict__ thr,
                                                       ushort_t* __restrict__ ksp,
                                                       ushort_t* __restrict__ vsp,
                                                       float* __restrict__ ebias) {
  const int b = blockIdx.x;
  const int j = b >> 3;
  const int h = b & 7;
  const int t = threadIdx.x;
  float ipv = imp[h * S_ + j];
  bool dense = (j >= S_ - W_) || (j < 2);
  int lvl = dense ? 0 : ((ipv >= thr[0]) ? 0 : ((ipv < thr[1]) ? 2 : 1));
  if (t == 0) ebias[h * S_ + j] = (lvl == 2) ? -INFINITY : 0.0f;
  __shared__ float av[128];
  __shared__ float thv;
  size_t base_in = (size_t)j * KLD_ + h * D_;
  size_t base_out = (size_t)j * NKV_ + h * D_;
  float kvv = kv[base_in + t];
  av[t] = fabsf(kvv);
  __syncthreads();
  {
    float at = av[t]; int cnt = 0;
    for (int m = 0; m < 128; ++m) { float am = av[m]; cnt += (am < at) || (am == at && m < t); }
    if (cnt == THR_IDX_) thv = at;
  }
  __syncthreads();
  {
    bool keep = (lvl == 0) || (lvl == 1 && fabsf(kvv) >= thv);
    ksp[base_out + t] = f2bf(keep ? kvv : 0.0f);
  }
  __syncthreads();
  float vvv = kv[base_in + 1024 + t];
  av[t] = fabsf(vvv);
  __syncthreads();
  {
    float at = av[t]; int cnt = 0;
    for (int m = 0; m < 128; ++m) { float am = av[m]; cnt += (am < at) || (am == at && m < t); }
    if (cnt == THR_IDX_) thv = at;
  }
  __syncthreads();
  {
    bool keep = (lvl == 0) || (lvl == 1 && fabsf(vvv) >= thv);
    vsp[base_out + t] = f2bf(keep ? vvv : 0.0f);
  }
}

// ---------------- V transpose ----------------
__global__ __launch_bounds__(256) void vtrans_kernel(const ushort_t* __restrict__ vsp,
                                                     ushort_t* __restrict__ vspT) {
  __shared__ ushort_t tl[64][136];
  const int jt = blockIdx.x;
  const int hk = blockIdx.y;
  const int t = threadIdx.x;
#pragma unroll
  for (int i = 0; i < 4; ++i) {
    int idx = i * 256 + t;
    int j = idx >> 4, c = idx & 15;
    *(u16x8*)&tl[j][c * 8] = *(const u16x8*)(vsp + (size_t)(jt * 64 + j) * NKV_ + hk * 128 + c * 8);
  }
  __syncthreads();
  int d = t >> 1, j0 = (t & 1) * 32;
#pragma unroll
  for (int jj = 0; jj < 4; ++jj) {
    u16x8 v;
#pragma unroll
    for (int e = 0; e < 8; ++e) v[e] = tl[j0 + jj * 8 + e][d];
    *(u16x8*)(vspT + ((size_t)hk * 128 + d) * S_ + jt * 64 + j0 + jj * 8) = v;
  }
}

// ---------------- main attention ----------------
#define SPAD_ 66
__global__ __launch_bounds__(256) void attn_kernel(const ushort_t* __restrict__ qbp,
                                                   const ushort_t* __restrict__ ksp,
                                                   const ushort_t* __restrict__ vspT,
                                                   const float* __restrict__ ebias,
                                                   ushort_t* __restrict__ ob16) {
  __shared__ ushort_t k_lds[64 * 128];
  __shared__ ushort_t vT_lds[128 * 64];
  __shared__ float s_lds[4][16][SPAD_];
  const int b = blockIdx.x;
  const int xcd = b & 7;
  const int idx = b >> 3;
  const int h = xcd * 4 + (idx >> 4);
  const int p = idx & 15;
  const int hk = h >> 2;
  const int t = threadIdx.x;
  const int w = t >> 6, lane = t & 63;
  const int lc = lane & 15, lg = lane >> 4;

  const ushort_t* kbase = ksp + hk * D_;
  const ushort_t* vbase = vspT + (size_t)hk * D_ * S_;

  for (int strip = 0; strip < 2; ++strip) {
    const int qb = (strip == 0) ? p : 31 - p;
    const int q0 = qb * 64 + w * 16;
    s16x8 qfrag[4];
#pragma unroll
    for (int db = 0; db < 4; ++db)
      qfrag[db] = *(const s16x8*)(qbp + (size_t)(q0 + lc) * NQ_ + h * D_ + db * 32 + lg * 8);

    f32x4 o[8];
#pragma unroll
    for (int n = 0; n < 8; ++n) o[n] = 0.f;
    float mr[4] = {-INFINITY, -INFINITY, -INFINITY, -INFINITY};
    float lr[4] = {0.f, 0.f, 0.f, 0.f};

    const int ntj = qb + 1;
    for (int tj = 0; tj < ntj; ++tj) {
      const int j0 = tj * 64;
      __syncthreads();
#pragma unroll
      for (int i = 0; i < 4; ++i) {
        int slot = i * 256 + w * 64 + lane;
        int row = slot >> 4, c = slot & 15;
        const ushort_t* gp = kbase + (size_t)(j0 + row) * NKV_ + ((c ^ (row & 7)) * 8);
        gload_lds16(gp, &k_lds[(i * 256 + w * 64) * 8]);
      }
#pragma unroll
      for (int i = 0; i < 4; ++i) {
        int slot = i * 256 + w * 64 + lane;
        int d = slot >> 3, c = slot & 7;
        const ushort_t* gp = vbase + (size_t)d * S_ + j0 + ((c ^ (d & 7)) * 8);
        gload_lds16(gp, &vT_lds[(i * 256 + w * 64) * 8]);
      }
      __syncthreads();

      f32x4 sfr[4];
#pragma unroll
      for (int js = 0; js < 4; ++js) sfr[js] = 0.f;
#pragma unroll
      for (int js = 0; js < 4; ++js) {
        int row = js * 16 + lc;
#pragma unroll
        for (int db = 0; db < 4; ++db) {
          s16x8 kf = *(const s16x8*)&k_lds[row * 128 + (((db * 4 + lg) ^ (lc & 7)) * 8)];
          sfr[js] = __builtin_amdgcn_mfma_f32_16x16x32_bf16(qfrag[db], kf, sfr[js], 0, 0, 0);
        }
      }
      float eb[4];
#pragma unroll
      for (int js = 0; js < 4; ++js) eb[js] = ebias[hk * S_ + j0 + js * 16 + lc];

      const bool diag = (tj == qb);
      float sclv[4];
#pragma unroll
      for (int r = 0; r < 4; ++r) {
        float sv[4];
#pragma unroll
        for (int js = 0; js < 4; ++js) sv[js] = sfr[js][r] * SCALE_ + eb[js];
        if (diag) {
          int qrow = w * 16 + lg * 4 + r;
#pragma unroll
          for (int js = 0; js < 4; ++js)
            if (js * 16 + lc > qrow) sv[js] = -INFINITY;
        }
        float tm = fmaxf(fmaxf(sv[0], sv[1]), fmaxf(sv[2], sv[3]));
#pragma unroll
        for (int off = 1; off < 16; off <<= 1) tm = fmaxf(tm, __shfl_xor(tm, off, 64));
        float mnew = fmaxf(mr[r], tm);
        float scl = __expf(mr[r] - mnew);
        float ps = 0.f;
#pragma unroll
        for (int js = 0; js < 4; ++js) {
          float e = __expf(sv[js] - mnew);
          s_lds[w][lg * 4 + r][js * 16 + lc] = e;
          ps += e;
        }
#pragma unroll
        for (int off = 1; off < 16; off <<= 1) ps += __shfl_xor(ps, off, 64);
        lr[r] = lr[r] * scl + ps;
        mr[r] = mnew;
        sclv[r] = scl;
      }
#pragma unroll
      for (int n = 0; n < 8; ++n) {
        f32x4 ov = o[n];
#pragma unroll
        for (int r = 0; r < 4; ++r) ov[r] *= sclv[r];
        o[n] = ov;
      }
      asm volatile("s_waitcnt lgkmcnt(0)" ::: "memory");
      s16x8 pa[2];
#pragma unroll
      for (int ks = 0; ks < 2; ++ks) {
        float pv[8];
        *(f32x4*)&pv[0] = *(const f32x4*)&s_lds[w][lc][ks * 32 + lg * 8];
        *(f32x4*)&pv[4] = *(const f32x4*)&s_lds[w][lc][ks * 32 + lg * 8 + 4];
        s16x8 pk;
#pragma unroll
        for (int e = 0; e < 8; ++e) pk[e] = (short)f2bf(pv[e]);
        pa[ks] = pk;
      }
#pragma unroll
      for (int n = 0; n < 8; ++n) {
        int d = n * 16 + lc;
#pragma unroll
        for (int ks = 0; ks < 2; ++ks) {
          s16x8 vf = *(const s16x8*)&vT_lds[d * 64 + (((ks * 4 + lg) ^ (lc & 7)) * 8)];
          o[n] = __builtin_amdgcn_mfma_f32_16x16x32_bf16(pa[ks], vf, o[n], 0, 0, 0);
        }
      }
    }
#pragma unroll
    for (int r = 0; r < 4; ++r) {
      float rinv = 1.0f / lr[r];
      int row = q0 + lg * 4 + r;
#pragma unroll
      for (int n = 0; n < 8; ++n)
        ob16[(size_t)row * NQ_ + h * D_ + n * 16 + lc] = f2bf(o[n][r] * rinv);
    }
  }
}

// ---------------- launcher ----------------
extern "C" void kernel_launch(void* const* d_in, const int* in_sizes, int n_in,
                              void* d_out, int out_size, void* d_ws, size_t ws_size,
                              hipStream_t stream) {
  (void)in_sizes; (void)n_in; (void)out_size; (void)ws_size;
  const float* hid = (const float*)d_in[0];
  const float* wq  = (const float*)d_in[1];
  const float* wk  = (const float*)d_in[2];
  const float* wv  = (const float*)d_in[3];
  const float* wo  = (const float*)d_in[4];
  float* out = (float*)d_out;
  char* ws = (char*)d_ws;
  const size_t MB = 1ull << 20;

  ushort_t* h0     = (ushort_t*)(ws + 0 * MB);
  ushort_t* h1     = (ushort_t*)(ws + 16 * MB);
  ushort_t* h2     = (ushort_t*)(ws + 32 * MB);
  ushort_t* wq0T   = (ushort_t*)(ws + 48 * MB);   // reused: qpart, then vspT
  float*    qpart  = (float*)(ws + 48 * MB);
  ushort_t* vspT   = (ushort_t*)(ws + 48 * MB);
  ushort_t* wkv0T  = (ushort_t*)(ws + 80 * MB);
  ushort_t* wkv1T  = (ushort_t*)(ws + 96 * MB);   // reused: qo0/1/2
  ushort_t* qo0    = (ushort_t*)(ws + 96 * MB);
  ushort_t* qo1    = (ushort_t*)(ws + 97 * MB);
  ushort_t* qo2    = (ushort_t*)(ws + 98 * MB);
  ushort_t* kb0    = (ushort_t*)(ws + 100 * MB);
  ushort_t* kb1    = (ushort_t*)(ws + 104 * MB);
  ushort_t* kb2    = (ushort_t*)(ws + 108 * MB);
  ushort_t* wkv2T  = (ushort_t*)(ws + 112 * MB);  // reused: s_obs (112-146)
  float*    s_obs  = (float*)(ws + 112 * MB);
  float*    qf     = (float*)(ws + 128 * MB);
  float*    kvf    = (float*)(ws + 160 * MB);
  ushort_t* qb16   = (ushort_t*)(ws + 176 * MB);
  float*    qobs   = (float*)(ws + 192 * MB);
  ushort_t* ksp    = (ushort_t*)(ws + 195 * MB);
  ushort_t* vsp    = (ushort_t*)(ws + 199 * MB);
  ushort_t* ob16   = (ushort_t*)(ws + 203 * MB);
  float*    impv   = (float*)(ws + 227 * MB);
  float*    eb     = (float*)(ws + 228 * MB);
  float*    invf   = (float*)(ws + 229 * MB);
  float*    thr    = (float*)(ws + 229 * MB + 4096);
  unsigned* prefix = (unsigned*)(ws + 229 * MB + 8192);
  unsigned* kneed  = (unsigned*)(ws + 229 * MB + 12288);
  unsigned* hist   = (unsigned*)(ws + 229 * MB + 16384);
  float*    mxbuf  = (float*)(ws + 229 * MB + 24576);
  float*    dinvb  = (float*)(ws + 229 * MB + 49152);
  ushort_t* woT    = (ushort_t*)(ws + 0 * MB);

  // 1) splits
  split3_kernel<<<(S_ * HID_ / 4 + 255) / 256, 256, 0, stream>>>(hid, h0, h1, h2, S_ * HID_ / 4);
  splitT_kernel<<<dim3(NQ_ / 64, HID_ / 64), 256, 0, stream>>>(wq, NQ_, wq0T, nullptr, nullptr);
  splitT_kernel<<<dim3(NKV_ / 64, HID_ / 64), 256, 0, stream>>>(wk, NKV_, wkv0T, wkv1T, wkv2T);
  splitT_kernel<<<dim3(NKV_ / 64, HID_ / 64), 256, 0, stream>>>(
      wv, NKV_, wkv0T + (size_t)NKV_ * HID_, wkv1T + (size_t)NKV_ * HID_, wkv2T + (size_t)NKV_ * HID_);

  // 2) K|V 6-product bf16 (fp32-grade)
  gemm_bt<1><<<dim3(2048 / 128, S_ / 128), 256, 0, stream>>>(h0, h1, wkv0T, wkv1T, kvf, S_, 2048, HID_);
  gemm_bt<2><<<dim3(2048 / 128, S_ / 128), 256, 0, stream>>>(h0, h2, wkv0T, wkv2T, kvf, S_, 2048, HID_);

  // 3) Q main GEMM (bf16 path)
  gemm_bt<0><<<dim3(NQ_ / 128, S_ / 128), 256, 0, stream>>>(h0, nullptr, wq0T, nullptr, qf, S_, NQ_, HID_);

  // 4) obs-Q exact fp32
  gemm_obsq<<<dim3(NQ_ / 128, 1, 16), 256, 0, stream>>>(hid + (size_t)(S_ - OBS_) * HID_, wq, qpart);
  reduce16_kernel<<<(OBS_ * NQ_ + 255) / 256, 256, 0, stream>>>(qpart, qobs, OBS_ * NQ_);

  // 5) wo transpose+cast
  splitT_kernel<<<dim3(HID_ / 64, HID_ / 64), 256, 0, stream>>>(wo, HID_, woT, nullptr, nullptr);

  // 6) RoPE
  freq_kernel<<<1, 64, 0, stream>>>(invf);
  rope_kernel<<<(S_ * HQ_ * 64 + 255) / 256, 256, 0, stream>>>(qf, qb16, invf, HQ_, NQ_, 0, S_ * HQ_ * 64);
  rope_kernel<<<(S_ * HKV_ * 64 + 255) / 256, 256, 0, stream>>>(kvf, nullptr, invf, HKV_, KLD_, 0, S_ * HKV_ * 64);
  rope_kernel<<<(OBS_ * HQ_ * 64 + 255) / 256, 256, 0, stream>>>(qobs, nullptr, invf, HQ_, NQ_, S_ - OBS_, OBS_ * HQ_ * 64);

  // 7) obs importance via MFMA GEMM + row/col reductions
  splitq_obs<<<(OBS_ * NQ_ / 4 + 255) / 256, 256, 0, stream>>>(qobs, qo0, qo1, qo2);
  splitk_obs<<<(S_ * NKV_ / 4 + 255) / 256, 256, 0, stream>>>(kvf, kb0, kb1, kb2);
  gemm_btz<1><<<dim3(16, 4, 8), 256, 0, stream>>>(qo0, qo1, kb0, kb1, s_obs, 512, S_, D_);
  gemm_btz<2><<<dim3(16, 4, 8), 256, 0, stream>>>(qo0, qo2, kb0, kb2, s_obs, 512, S_, D_);
  rowstat_kernel<<<1024, 256, 0, stream>>>(s_obs, mxbuf, dinvb);
  colsum_kernel<<<dim3(8, 8), 256, 0, stream>>>(s_obs, mxbuf, dinvb, impv);

  radix_init<<<1, 64, 0, stream>>>(prefix, kneed);
  for (int pass = 0; pass < 4; ++pass) {
    hipMemsetAsync(hist, 0, 4096, stream);
    radix_hist<<<(NC_ + 255) / 256, 256, 0, stream>>>(impv, prefix, pass, hist);
    radix_scan<<<1, 64, 0, stream>>>(hist, prefix, kneed, pass, thr);
  }

  // 8) sparsify + V-transpose + attention + out projection
  sparsify_kernel<<<S_ * HKV_, 128, 0, stream>>>(kvf, impv, thr, ksp, vsp, eb);
  vtrans_kernel<<<dim3(S_ / 64, HKV_), 256, 0, stream>>>(vsp, vspT);
  attn_kernel<<<512, 256, 0, stream>>>(qb16, ksp, vspT, eb, ob16);
  gemm_bt<0><<<dim3(HID_ / 128, S_ / 128), 256, 0, stream>>>(ob16, nullptr, woT, nullptr, out, S_, HID_, HID_);
}

// Round 5
// 1008.521 us; speedup vs baseline: 1.1001x; 1.1001x over previous
//
#include <hip/hip_runtime.h>
#include <hip/hip_bf16.h>
#include <math.h>

#define S_    2048
#define HID_  4096
#define HQ_   32
#define HKV_  8
#define D_    128
#define G_    4
#define OBS_  128
#define W_    32
#define NKV_  1024
#define NQ_   4096
#define KLD_  2048
#define SCALE_ 0.08838834764831845f
#define THR_IDX_ 89
#define NC_   16128

typedef __attribute__((ext_vector_type(4))) float f32x4;
typedef __attribute__((ext_vector_type(8))) short s16x8;
typedef __attribute__((ext_vector_type(8))) unsigned short u16x8;
typedef __attribute__((ext_vector_type(4))) unsigned short u16x4;
typedef unsigned short ushort_t;

__device__ __forceinline__ unsigned short f2bf(float x) {
  union { float f; unsigned u; } v; v.f = x;
  unsigned r = v.u + 0x7FFFu + ((v.u >> 16) & 1u);
  return (unsigned short)(r >> 16);
}
__device__ __forceinline__ float bf2f(unsigned short b) {
  union { unsigned u; float f; } v; v.u = ((unsigned)b) << 16;
  return v.f;
}
__device__ __forceinline__ void gload_lds16(const void* g, void* l) {
  __builtin_amdgcn_global_load_lds((const __attribute__((address_space(1))) unsigned int*)g,
                                   (__attribute__((address_space(3))) unsigned int*)l, 16, 0, 0);
}

// ---------------- split fp32 -> 3 bf16 terms ----------------
__global__ __launch_bounds__(256) void split3_kernel(const float* __restrict__ src,
                                                     ushort_t* __restrict__ d0,
                                                     ushort_t* __restrict__ d1,
                                                     ushort_t* __restrict__ d2, int n4) {
  int idx = blockIdx.x * 256 + threadIdx.x;
  if (idx >= n4) return;
  float4 v = ((const float4*)src)[idx];
  u16x4 o0, o1, o2;
  float xs[4] = {v.x, v.y, v.z, v.w};
#pragma unroll
  for (int e = 0; e < 4; ++e) {
    float x = xs[e];
    unsigned short b0 = f2bf(x);
    float r = x - bf2f(b0);
    unsigned short b1 = f2bf(r);
    float r2 = r - bf2f(b1);
    unsigned short b2 = f2bf(r2);
    o0[e] = b0; o1[e] = b1; o2[e] = b2;
  }
  *(u16x4*)(d0 + (size_t)idx * 4) = o0;
  *(u16x4*)(d1 + (size_t)idx * 4) = o1;
  *(u16x4*)(d2 + (size_t)idx * 4) = o2;
}

// ---------------- split + transpose weights ----------------
__global__ __launch_bounds__(256) void splitT_kernel(const float* __restrict__ src, int N,
                                                     ushort_t* __restrict__ t0,
                                                     ushort_t* __restrict__ t1,
                                                     ushort_t* __restrict__ t2) {
  __shared__ float tile[64][65];
  const int t = threadIdx.x;
  const int n0 = blockIdx.x * 64, k0 = blockIdx.y * 64;
#pragma unroll
  for (int i = 0; i < 16; ++i) {
    int idx = i * 256 + t;
    int r = idx >> 6, c = idx & 63;
    tile[r][c] = src[(size_t)(k0 + r) * N + n0 + c];
  }
  __syncthreads();
#pragma unroll
  for (int i = 0; i < 16; ++i) {
    int idx = i * 256 + t;
    int n = idx >> 6, kk = idx & 63;
    float x = tile[kk][n];
    unsigned short b0 = f2bf(x);
    size_t o = (size_t)(n0 + n) * HID_ + k0 + kk;
    t0[o] = b0;
    if (t1) {
      float r = x - bf2f(b0);
      unsigned short b1 = f2bf(r);
      t1[o] = b1;
      float r2 = r - bf2f(b1);
      t2[o] = f2bf(r2);
    }
  }
}

// ---------------- unified bf16 MFMA GEMM ----------------
template<int MODE>
__global__ __launch_bounds__(256) void gemm_bt(const ushort_t* __restrict__ A0,
                                               const ushort_t* __restrict__ A1,
                                               const ushort_t* __restrict__ B0,
                                               const ushort_t* __restrict__ B1,
                                               float* __restrict__ C,
                                               int M, int N, int K) {
  constexpr int NT = (MODE == 0) ? 2 : 4;
  __shared__ ushort_t lds[NT * 128 * 64];
  const int t = threadIdx.x;
  const int wave = t >> 6, lane = t & 63;
  const int lc = lane & 15, lg = lane >> 4;
  const int bm = blockIdx.y, bn = blockIdx.x;
  const int wm = wave >> 1, wn = wave & 1;
  const int srow = t >> 3;
  const int schunk = t & 7;

  f32x4 acc[4][4];
#pragma unroll
  for (int fi = 0; fi < 4; ++fi)
#pragma unroll
    for (int fj = 0; fj < 4; ++fj) acc[fi][fj] = 0.f;

  for (int kb = 0; kb < K / 64; ++kb) {
    __syncthreads();
#pragma unroll
    for (int tid = 0; tid < NT; ++tid) {
      const ushort_t* src = (tid == 0) ? A0 : (tid == 1) ? B0 : (tid == 2) ? A1 : B1;
      const int rb = (tid == 0 || tid == 2) ? bm : bn;
#pragma unroll
      for (int g = 0; g < 4; ++g) {
        int row = g * 32 + srow;
        int sw = schunk ^ (row & 7);
        const ushort_t* gp = src + (size_t)(rb * 128 + row) * K + kb * 64 + sw * 8;
        ushort_t* lp = lds + tid * 8192 + g * 2048 + wave * 512;
        gload_lds16(gp, lp);
      }
    }
    __syncthreads();
#pragma unroll
    for (int ks = 0; ks < 2; ++ks) {
      s16x8 a0f[4], b0f[4], a1f[4], b1f[4];
#pragma unroll
      for (int f = 0; f < 4; ++f) {
        int ra = wm * 64 + f * 16 + lc;
        int ca = ((ks * 4 + lg) ^ (ra & 7)) * 8;
        a0f[f] = *(const s16x8*)(lds + 0 * 8192 + ra * 64 + ca);
        int rb2 = wn * 64 + f * 16 + lc;
        int cb = ((ks * 4 + lg) ^ (rb2 & 7)) * 8;
        b0f[f] = *(const s16x8*)(lds + 1 * 8192 + rb2 * 64 + cb);
        if constexpr (MODE >= 1) {
          a1f[f] = *(const s16x8*)(lds + 2 * 8192 + ra * 64 + ca);
          b1f[f] = *(const s16x8*)(lds + 3 * 8192 + rb2 * 64 + cb);
        }
      }
#pragma unroll
      for (int fi = 0; fi < 4; ++fi)
#pragma unroll
        for (int fj = 0; fj < 4; ++fj) {
          if constexpr (MODE == 0) {
            acc[fi][fj] = __builtin_amdgcn_mfma_f32_16x16x32_bf16(a0f[fi], b0f[fj], acc[fi][fj], 0, 0, 0);
          } else if constexpr (MODE == 1) {
            acc[fi][fj] = __builtin_amdgcn_mfma_f32_16x16x32_bf16(a0f[fi], b0f[fj], acc[fi][fj], 0, 0, 0);
            acc[fi][fj] = __builtin_amdgcn_mfma_f32_16x16x32_bf16(a0f[fi], b1f[fj], acc[fi][fj], 0, 0, 0);
            acc[fi][fj] = __builtin_amdgcn_mfma_f32_16x16x32_bf16(a1f[fi], b0f[fj], acc[fi][fj], 0, 0, 0);
            acc[fi][fj] = __builtin_amdgcn_mfma_f32_16x16x32_bf16(a1f[fi], b1f[fj], acc[fi][fj], 0, 0, 0);
          } else {
            acc[fi][fj] = __builtin_amdgcn_mfma_f32_16x16x32_bf16(a0f[fi], b1f[fj], acc[fi][fj], 0, 0, 0);
            acc[fi][fj] = __builtin_amdgcn_mfma_f32_16x16x32_bf16(a1f[fi], b0f[fj], acc[fi][fj], 0, 0, 0);
          }
        }
    }
  }
#pragma unroll
  for (int fi = 0; fi < 4; ++fi)
#pragma unroll
    for (int fj = 0; fj < 4; ++fj)
#pragma unroll
      for (int r = 0; r < 4; ++r) {
        size_t o = (size_t)(bm * 128 + wm * 64 + fi * 16 + lg * 4 + r) * N +
                   bn * 128 + wn * 64 + fj * 16 + lc;
        if constexpr (MODE == 2) C[o] += acc[fi][fj][r];
        else C[o] = acc[fi][fj][r];
      }
}

// ---------------- z-batched variant for obs GEMM (per-kv-head) ----------------
template<int MODE>
__global__ __launch_bounds__(256) void gemm_btz(const ushort_t* __restrict__ A0g,
                                                const ushort_t* __restrict__ A1g,
                                                const ushort_t* __restrict__ B0g,
                                                const ushort_t* __restrict__ B1g,
                                                float* __restrict__ Cg,
                                                int M, int N, int K) {
  __shared__ ushort_t lds[4 * 128 * 64];
  const int z = blockIdx.z;
  const ushort_t* A0 = A0g + (size_t)z * M * K;
  const ushort_t* A1 = A1g + (size_t)z * M * K;
  const ushort_t* B0 = B0g + (size_t)z * N * K;
  const ushort_t* B1 = B1g + (size_t)z * N * K;
  float* C = Cg + (size_t)z * M * N;
  const int t = threadIdx.x;
  const int wave = t >> 6, lane = t & 63;
  const int lc = lane & 15, lg = lane >> 4;
  const int bm = blockIdx.y, bn = blockIdx.x;
  const int wm = wave >> 1, wn = wave & 1;
  const int srow = t >> 3;
  const int schunk = t & 7;

  f32x4 acc[4][4];
#pragma unroll
  for (int fi = 0; fi < 4; ++fi)
#pragma unroll
    for (int fj = 0; fj < 4; ++fj) acc[fi][fj] = 0.f;

  for (int kb = 0; kb < K / 64; ++kb) {
    __syncthreads();
#pragma unroll
    for (int tid = 0; tid < 4; ++tid) {
      const ushort_t* src = (tid == 0) ? A0 : (tid == 1) ? B0 : (tid == 2) ? A1 : B1;
      const int rb = (tid == 0 || tid == 2) ? bm : bn;
#pragma unroll
      for (int g = 0; g < 4; ++g) {
        int row = g * 32 + srow;
        int sw = schunk ^ (row & 7);
        const ushort_t* gp = src + (size_t)(rb * 128 + row) * K + kb * 64 + sw * 8;
        ushort_t* lp = lds + tid * 8192 + g * 2048 + wave * 512;
        gload_lds16(gp, lp);
      }
    }
    __syncthreads();
#pragma unroll
    for (int ks = 0; ks < 2; ++ks) {
      s16x8 a0f[4], b0f[4], a1f[4], b1f[4];
#pragma unroll
      for (int f = 0; f < 4; ++f) {
        int ra = wm * 64 + f * 16 + lc;
        int ca = ((ks * 4 + lg) ^ (ra & 7)) * 8;
        a0f[f] = *(const s16x8*)(lds + 0 * 8192 + ra * 64 + ca);
        int rb2 = wn * 64 + f * 16 + lc;
        int cb = ((ks * 4 + lg) ^ (rb2 & 7)) * 8;
        b0f[f] = *(const s16x8*)(lds + 1 * 8192 + rb2 * 64 + cb);
        a1f[f] = *(const s16x8*)(lds + 2 * 8192 + ra * 64 + ca);
        b1f[f] = *(const s16x8*)(lds + 3 * 8192 + rb2 * 64 + cb);
      }
#pragma unroll
      for (int fi = 0; fi < 4; ++fi)
#pragma unroll
        for (int fj = 0; fj < 4; ++fj) {
          if constexpr (MODE == 1) {
            acc[fi][fj] = __builtin_amdgcn_mfma_f32_16x16x32_bf16(a0f[fi], b0f[fj], acc[fi][fj], 0, 0, 0);
            acc[fi][fj] = __builtin_amdgcn_mfma_f32_16x16x32_bf16(a0f[fi], b1f[fj], acc[fi][fj], 0, 0, 0);
            acc[fi][fj] = __builtin_amdgcn_mfma_f32_16x16x32_bf16(a1f[fi], b0f[fj], acc[fi][fj], 0, 0, 0);
            acc[fi][fj] = __builtin_amdgcn_mfma_f32_16x16x32_bf16(a1f[fi], b1f[fj], acc[fi][fj], 0, 0, 0);
          } else {
            acc[fi][fj] = __builtin_amdgcn_mfma_f32_16x16x32_bf16(a0f[fi], b1f[fj], acc[fi][fj], 0, 0, 0);
            acc[fi][fj] = __builtin_amdgcn_mfma_f32_16x16x32_bf16(a1f[fi], b0f[fj], acc[fi][fj], 0, 0, 0);
          }
        }
    }
  }
#pragma unroll
  for (int fi = 0; fi < 4; ++fi)
#pragma unroll
    for (int fj = 0; fj < 4; ++fj)
#pragma unroll
      for (int r = 0; r < 4; ++r) {
        size_t o = (size_t)(bm * 128 + wm * 64 + fi * 16 + lg * 4 + r) * N +
                   bn * 128 + wn * 64 + fj * 16 + lc;
        if constexpr (MODE == 2) C[o] += acc[fi][fj][r];
        else C[o] = acc[fi][fj][r];
      }
}

// ---------------- obs-Q bf16 K-sliced GEMM: M=128, LDA=LDB=HID_, z = K-slice ----------------
template<int MODE>
__global__ __launch_bounds__(256) void gemm_btk(const ushort_t* __restrict__ A0,
                                                const ushort_t* __restrict__ A1,
                                                const ushort_t* __restrict__ B0,
                                                const ushort_t* __restrict__ B1,
                                                float* __restrict__ Cp, int N) {
  __shared__ ushort_t lds[4 * 128 * 64];
  const int z = blockIdx.z;
  const int t = threadIdx.x;
  const int wave = t >> 6, lane = t & 63;
  const int lc = lane & 15, lg = lane >> 4;
  const int bn = blockIdx.x;
  const int wm = wave >> 1, wn = wave & 1;
  const int srow = t >> 3;
  const int schunk = t & 7;
  float* C = Cp + (size_t)z * 128 * N;

  f32x4 acc[4][4];
#pragma unroll
  for (int fi = 0; fi < 4; ++fi)
#pragma unroll
    for (int fj = 0; fj < 4; ++fj) acc[fi][fj] = 0.f;

  for (int kb = z * 8; kb < z * 8 + 8; ++kb) {
    __syncthreads();
#pragma unroll
    for (int tid = 0; tid < 4; ++tid) {
      const ushort_t* src = (tid == 0) ? A0 : (tid == 1) ? B0 : (tid == 2) ? A1 : B1;
      const int rb = (tid == 0 || tid == 2) ? 0 : bn;
#pragma unroll
      for (int g = 0; g < 4; ++g) {
        int row = g * 32 + srow;
        int sw = schunk ^ (row & 7);
        const ushort_t* gp = src + (size_t)(rb * 128 + row) * HID_ + kb * 64 + sw * 8;
        ushort_t* lp = lds + tid * 8192 + g * 2048 + wave * 512;
        gload_lds16(gp, lp);
      }
    }
    __syncthreads();
#pragma unroll
    for (int ks = 0; ks < 2; ++ks) {
      s16x8 a0f[4], b0f[4], a1f[4], b1f[4];
#pragma unroll
      for (int f = 0; f < 4; ++f) {
        int ra = wm * 64 + f * 16 + lc;
        int ca = ((ks * 4 + lg) ^ (ra & 7)) * 8;
        a0f[f] = *(const s16x8*)(lds + 0 * 8192 + ra * 64 + ca);
        int rb2 = wn * 64 + f * 16 + lc;
        int cb = ((ks * 4 + lg) ^ (rb2 & 7)) * 8;
        b0f[f] = *(const s16x8*)(lds + 1 * 8192 + rb2 * 64 + cb);
        a1f[f] = *(const s16x8*)(lds + 2 * 8192 + ra * 64 + ca);
        b1f[f] = *(const s16x8*)(lds + 3 * 8192 + rb2 * 64 + cb);
      }
#pragma unroll
      for (int fi = 0; fi < 4; ++fi)
#pragma unroll
        for (int fj = 0; fj < 4; ++fj) {
          if constexpr (MODE == 1) {
            acc[fi][fj] = __builtin_amdgcn_mfma_f32_16x16x32_bf16(a0f[fi], b0f[fj], acc[fi][fj], 0, 0, 0);
            acc[fi][fj] = __builtin_amdgcn_mfma_f32_16x16x32_bf16(a0f[fi], b1f[fj], acc[fi][fj], 0, 0, 0);
            acc[fi][fj] = __builtin_amdgcn_mfma_f32_16x16x32_bf16(a1f[fi], b0f[fj], acc[fi][fj], 0, 0, 0);
            acc[fi][fj] = __builtin_amdgcn_mfma_f32_16x16x32_bf16(a1f[fi], b1f[fj], acc[fi][fj], 0, 0, 0);
          } else {
            acc[fi][fj] = __builtin_amdgcn_mfma_f32_16x16x32_bf16(a0f[fi], b1f[fj], acc[fi][fj], 0, 0, 0);
            acc[fi][fj] = __builtin_amdgcn_mfma_f32_16x16x32_bf16(a1f[fi], b0f[fj], acc[fi][fj], 0, 0, 0);
          }
        }
    }
  }
#pragma unroll
  for (int fi = 0; fi < 4; ++fi)
#pragma unroll
    for (int fj = 0; fj < 4; ++fj)
#pragma unroll
      for (int r = 0; r < 4; ++r) {
        size_t o = (size_t)(wm * 64 + fi * 16 + lg * 4 + r) * N +
                   bn * 128 + wn * 64 + fj * 16 + lc;
        if constexpr (MODE == 2) C[o] += acc[fi][fj][r];
        else C[o] = acc[fi][fj][r];
      }
}

__global__ void reduce8_kernel(const float* __restrict__ Cp, float* __restrict__ out, int n) {
  int idx = blockIdx.x * 256 + threadIdx.x;
  if (idx >= n) return;
  float s = 0.f;
#pragma unroll
  for (int z = 0; z < 8; ++z) s += Cp[(size_t)z * n + idx];
  out[idx] = s;
}

// ---------------- inv_freq ----------------
__global__ void freq_kernel(float* __restrict__ invf) {
  int j = threadIdx.x;
  if (j < 64) invf[j] = (float)(1.0 / pow(500000.0, (double)j / 64.0));
}

// ---------------- RoPE ----------------
__global__ void rope_kernel(float* __restrict__ X, ushort_t* __restrict__ Xb,
                            const float* __restrict__ invf, int H, int ld, int pos0, int total) {
  int idx = blockIdx.x * 256 + threadIdx.x;
  if (idx >= total) return;
  int j = idx & 63;
  int h = (idx >> 6) % H;
  int s = idx / (64 * H);
  float ang = (float)(pos0 + s) * invf[j];
  float sn, cs;
  sincosf(ang, &sn, &cs);
  size_t base = (size_t)s * ld + h * D_ + j;
  float x1 = X[base], x2 = X[base + 64];
  float o1 = x1 * cs - x2 * sn;
  float o2 = x2 * cs + x1 * sn;
  X[base] = o1; X[base + 64] = o2;
  if (Xb) { Xb[base] = f2bf(o1); Xb[base + 64] = f2bf(o2); }
}

// ---------------- obs-Q 3-split into [hk][g*128+i][d] ----------------
__global__ __launch_bounds__(256) void splitq_obs(const float* __restrict__ qobs,
                                                  ushort_t* __restrict__ q0,
                                                  ushort_t* __restrict__ q1,
                                                  ushort_t* __restrict__ q2) {
  int idx = blockIdx.x * 256 + threadIdx.x;
  if (idx >= OBS_ * NQ_ / 4) return;
  int idx4 = idx * 4;
  int i = idx4 >> 12;
  int col = idx4 & 4095;
  int hq = col >> 7, d = col & 127;
  int hk = hq >> 2, g = hq & 3;
  float4 v = *(const float4*)(qobs + (size_t)i * NQ_ + col);
  size_t o = (size_t)hk * 65536 + (size_t)(g * 128 + i) * 128 + d;
  float xs[4] = {v.x, v.y, v.z, v.w};
  u16x4 o0, o1, o2;
#pragma unroll
  for (int e = 0; e < 4; ++e) {
    float x = xs[e];
    unsigned short b0 = f2bf(x);
    float r = x - bf2f(b0);
    unsigned short b1 = f2bf(r);
    o0[e] = b0; o1[e] = b1; o2[e] = f2bf(r - bf2f(b1));
  }
  *(u16x4*)(q0 + o) = o0;
  *(u16x4*)(q1 + o) = o1;
  *(u16x4*)(q2 + o) = o2;
}

// ---------------- K 3-split into [hk][j][d] ----------------
__global__ __launch_bounds__(256) void splitk_obs(const float* __restrict__ kvf,
                                                  ushort_t* __restrict__ k0,
                                                  ushort_t* __restrict__ k1,
                                                  ushort_t* __restrict__ k2) {
  int idx = blockIdx.x * 256 + threadIdx.x;
  if (idx >= S_ * NKV_ / 4) return;
  int idx4 = idx * 4;
  int j = idx4 >> 10;
  int col = idx4 & 1023;
  int hk = col >> 7, d = col & 127;
  float4 v = *(const float4*)(kvf + (size_t)j * KLD_ + col);
  size_t o = (size_t)hk * 262144 + ((size_t)j << 7) + d;
  float xs[4] = {v.x, v.y, v.z, v.w};
  u16x4 o0, o1, o2;
#pragma unroll
  for (int e = 0; e < 4; ++e) {
    float x = xs[e];
    unsigned short b0 = f2bf(x);
    float r = x - bf2f(b0);
    unsigned short b1 = f2bf(r);
    o0[e] = b0; o1[e] = b1; o2[e] = f2bf(r - bf2f(b1));
  }
  *(u16x4*)(k0 + o) = o0;
  *(u16x4*)(k1 + o) = o1;
  *(u16x4*)(k2 + o) = o2;
}

// ---------------- per-row max + inv-denominator (causal) ----------------
__global__ __launch_bounds__(256) void rowstat_kernel(const float* __restrict__ s,
                                                      float* __restrict__ mx,
                                                      float* __restrict__ dinv) {
  const int row = blockIdx.x * 4 + (threadIdx.x >> 6);
  const int lane = threadIdx.x & 63;
  const int i = row & 127;
  const int jmax = S_ - OBS_ + i;
  const float* sp = s + (size_t)row * S_;
  float vals[32];
  float m = -INFINITY;
#pragma unroll
  for (int c = 0; c < 8; ++c) {
    int j0 = c * 256 + lane * 4;
    float4 v = *(const float4*)(sp + j0);
    float e0 = (j0 + 0 <= jmax) ? v.x * SCALE_ : -INFINITY;
    float e1 = (j0 + 1 <= jmax) ? v.y * SCALE_ : -INFINITY;
    float e2 = (j0 + 2 <= jmax) ? v.z * SCALE_ : -INFINITY;
    float e3 = (j0 + 3 <= jmax) ? v.w * SCALE_ : -INFINITY;
    vals[c * 4 + 0] = e0; vals[c * 4 + 1] = e1; vals[c * 4 + 2] = e2; vals[c * 4 + 3] = e3;
    m = fmaxf(m, fmaxf(fmaxf(e0, e1), fmaxf(e2, e3)));
  }
#pragma unroll
  for (int off = 1; off < 64; off <<= 1) m = fmaxf(m, __shfl_xor(m, off, 64));
  float ssum = 0.f;
#pragma unroll
  for (int c = 0; c < 32; ++c) ssum += expf(vals[c] - m);
#pragma unroll
  for (int off = 1; off < 64; off <<= 1) ssum += __shfl_xor(ssum, off, 64);
  if (lane == 0) { mx[row] = m; dinv[row] = 1.0f / ssum; }
}

// ---------------- column-sum stage 1: 64-row chunks ----------------
__global__ __launch_bounds__(256) void colsum_part(const float* __restrict__ s,
                                                   const float* __restrict__ mx,
                                                   const float* __restrict__ dinv,
                                                   float* __restrict__ part) {
  __shared__ float mxl[64], dvl[64];
  const int jt = blockIdx.x, hk = blockIdx.y, rc = blockIdx.z;
  const int t = threadIdx.x;
  if (t < 64) {
    mxl[t] = mx[hk * 512 + rc * 64 + t];
    dvl[t] = dinv[hk * 512 + rc * 64 + t];
  }
  __syncthreads();
  const int j = jt * 256 + t;
  const float* sp = s + ((size_t)hk * 512 + rc * 64) * S_ + j;
  float acc = 0.f;
  for (int rr = 0; rr < 64; ++rr) {
    int i = (rc * 64 + rr) & 127;
    if (j <= S_ - OBS_ + i)
      acc += expf(sp[(size_t)rr * S_] * SCALE_ - mxl[rr]) * dvl[rr];
  }
  part[((size_t)rc * 8 + hk) * S_ + j] = acc;
}

// ---------------- column-sum stage 2: fixed-order chunk reduce -> imp ----------------
__global__ void colsum_fin(const float* __restrict__ part, float* __restrict__ imp) {
  int idx = blockIdx.x * 256 + threadIdx.x;   // 0..16383
  int hk = idx >> 11, j = idx & 2047;
  float acc = 0.f;
#pragma unroll
  for (int rc = 0; rc < 8; ++rc) acc += part[((size_t)rc * 8 + hk) * S_ + j];
  float cnt = (float)min(OBS_, S_ - j);
  imp[idx] = acc * 0.25f / cnt;
}

// ---------------- radix select ----------------
__global__ void radix_init(unsigned* prefix, unsigned* kneed) {
  if (threadIdx.x == 0) {
    prefix[0] = prefix[1] = prefix[2] = prefix[3] = 0u;
    kneed[0] = 3225u; kneed[1] = 3226u; kneed[2] = 15320u; kneed[3] = 15321u;
  }
}
__global__ __launch_bounds__(256) void radix_hist(const float* __restrict__ imp,
                                                  const unsigned* __restrict__ prefix,
                                                  int pass, unsigned* __restrict__ hist) {
  __shared__ unsigned lh[1024];
  int t = threadIdx.x;
  for (int i = t; i < 1024; i += 256) lh[i] = 0u;
  __syncthreads();
  int idx = blockIdx.x * 256 + t;
  if (idx < NC_) {
    int h = idx / (S_ - W_), j = idx - h * (S_ - W_);
    union { float f; unsigned u; } cv; cv.f = imp[h * S_ + j];
    unsigned u = cv.u;
    int shift = 24 - pass * 8;
#pragma unroll
    for (int t4 = 0; t4 < 4; ++t4) {
      bool m = (pass == 0) || ((u >> (shift + 8)) == (prefix[t4] >> (shift + 8)));
      if (m) atomicAdd(&lh[t4 * 256 + ((u >> shift) & 255u)], 1u);
    }
  }
  __syncthreads();
  for (int i = t; i < 1024; i += 256) if (lh[i]) atomicAdd(&hist[i], lh[i]);
}
__global__ void radix_scan(const unsigned* __restrict__ hist, unsigned* prefix,
                           unsigned* kneed, int pass, float* thr) {
  int t = threadIdx.x;
  __shared__ unsigned selbits[4];
  if (t < 4) {
    unsigned need = kneed[t];
    unsigned cum = 0;
    int shift = 24 - pass * 8;
    unsigned pfx = prefix[t];
    for (int d = 0; d < 256; ++d) {
      unsigned c = hist[t * 256 + d];
      if (cum + c > need) { pfx |= ((unsigned)d) << shift; kneed[t] = need - cum; break; }
      cum += c;
    }
    prefix[t] = pfx;
    selbits[t] = pfx;
  }
  __syncthreads();
  if (pass == 3 && t == 0) {
    union { unsigned u; float f; } c0, c1, c2, c3;
    c0.u = selbits[0]; c1.u = selbits[1]; c2.u = selbits[2]; c3.u = selbits[3];
    double fl = 0.2 * (double)(NC_ - 1) - 3225.0;
    double fh = 0.95 * (double)(NC_ - 1) - 15320.0;
    thr[0] = (float)((double)c2.f + ((double)c3.f - (double)c2.f) * fh);
    thr[1] = (float)((double)c0.f + ((double)c1.f - (double)c0.f) * fl);
  }
}

// ---------------- sparsify ----------------
__global__ __launch_bounds__(128) void sparsify_kernel(const float* __restrict__ kv,
                                                       const float* __restrict__ imp,
                                                       const float* __restrict__ thr,
                                                       ushort_t* __restrict__ ksp,
                                                       ushort_t* __restrict__ vsp,
                                                       float* __restrict__ ebias) {
  const int b = blockIdx.x;
  const int j = b >> 3;
  const int h = b & 7;
  const int t = threadIdx.x;
  float ipv = imp[h * S_ + j];
  bool dense = (j >= S_ - W_) || (j < 2);
  int lvl = dense ? 0 : ((ipv >= thr[0]) ? 0 : ((ipv < thr[1]) ? 2 : 1));
  if (t == 0) ebias[h * S_ + j] = (lvl == 2) ? -INFINITY : 0.0f;
  __shared__ float av[128];
  __shared__ float thv;
  size_t base_in = (size_t)j * KLD_ + h * D_;
  size_t base_out = (size_t)j * NKV_ + h * D_;
  float kvv = kv[base_in + t];
  av[t] = fabsf(kvv);
  __syncthreads();
  {
    float at = av[t]; int cnt = 0;
    for (int m = 0; m < 128; ++m) { float am = av[m]; cnt += (am < at) || (am == at && m < t); }
    if (cnt == THR_IDX_) thv = at;
  }
  __syncthreads();
  {
    bool keep = (lvl == 0) || (lvl == 1 && fabsf(kvv) >= thv);
    ksp[base_out + t] = f2bf(keep ? kvv : 0.0f);
  }
  __syncthreads();
  float vvv = kv[base_in + 1024 + t];
  av[t] = fabsf(vvv);
  __syncthreads();
  {
    float at = av[t]; int cnt = 0;
    for (int m = 0; m < 128; ++m) { float am = av[m]; cnt += (am < at) || (am == at && m < t); }
    if (cnt == THR_IDX_) thv = at;
  }
  __syncthreads();
  {
    bool keep = (lvl == 0) || (lvl == 1 && fabsf(vvv) >= thv);
    vsp[base_out + t] = f2bf(keep ? vvv : 0.0f);
  }
}

// ---------------- V transpose ----------------
__global__ __launch_bounds__(256) void vtrans_kernel(const ushort_t* __restrict__ vsp,
                                                     ushort_t* __restrict__ vspT) {
  __shared__ ushort_t tl[64][136];
  const int jt = blockIdx.x;
  const int hk = blockIdx.y;
  const int t = threadIdx.x;
#pragma unroll
  for (int i = 0; i < 4; ++i) {
    int idx = i * 256 + t;
    int j = idx >> 4, c = idx & 15;
    *(u16x8*)&tl[j][c * 8] = *(const u16x8*)(vsp + (size_t)(jt * 64 + j) * NKV_ + hk * 128 + c * 8);
  }
  __syncthreads();
  int d = t >> 1, j0 = (t & 1) * 32;
#pragma unroll
  for (int jj = 0; jj < 4; ++jj) {
    u16x8 v;
#pragma unroll
    for (int e = 0; e < 8; ++e) v[e] = tl[j0 + jj * 8 + e][d];
    *(u16x8*)(vspT + ((size_t)hk * 128 + d) * S_ + jt * 64 + j0 + jj * 8) = v;
  }
}

// ---------------- main attention ----------------
#define SPAD_ 66
__global__ __launch_bounds__(256) void attn_kernel(const ushort_t* __restrict__ qbp,
                                                   const ushort_t* __restrict__ ksp,
                                                   const ushort_t* __restrict__ vspT,
                                                   const float* __restrict__ ebias,
                                                   ushort_t* __restrict__ ob16) {
  __shared__ ushort_t k_lds[64 * 128];
  __shared__ ushort_t vT_lds[128 * 64];
  __shared__ float s_lds[4][16][SPAD_];
  const int b = blockIdx.x;
  const int xcd = b & 7;
  const int idx = b >> 3;
  const int h = xcd * 4 + (idx >> 4);
  const int p = idx & 15;
  const int hk = h >> 2;
  const int t = threadIdx.x;
  const int w = t >> 6, lane = t & 63;
  const int lc = lane & 15, lg = lane >> 4;

  const ushort_t* kbase = ksp + hk * D_;
  const ushort_t* vbase = vspT + (size_t)hk * D_ * S_;

  for (int strip = 0; strip < 2; ++strip) {
    const int qb = (strip == 0) ? p : 31 - p;
    const int q0 = qb * 64 + w * 16;
    s16x8 qfrag[4];
#pragma unroll
    for (int db = 0; db < 4; ++db)
      qfrag[db] = *(const s16x8*)(qbp + (size_t)(q0 + lc) * NQ_ + h * D_ + db * 32 + lg * 8);

    f32x4 o[8];
#pragma unroll
    for (int n = 0; n < 8; ++n) o[n] = 0.f;
    float mr[4] = {-INFINITY, -INFINITY, -INFINITY, -INFINITY};
    float lr[4] = {0.f, 0.f, 0.f, 0.f};

    const int ntj = qb + 1;
    for (int tj = 0; tj < ntj; ++tj) {
      const int j0 = tj * 64;
      __syncthreads();
#pragma unroll
      for (int i = 0; i < 4; ++i) {
        int slot = i * 256 + w * 64 + lane;
        int row = slot >> 4, c = slot & 15;
        const ushort_t* gp = kbase + (size_t)(j0 + row) * NKV_ + ((c ^ (row & 7)) * 8);
        gload_lds16(gp, &k_lds[(i * 256 + w * 64) * 8]);
      }
#pragma unroll
      for (int i = 0; i < 4; ++i) {
        int slot = i * 256 + w * 64 + lane;
        int d = slot >> 3, c = slot & 7;
        const ushort_t* gp = vbase + (size_t)d * S_ + j0 + ((c ^ (d & 7)) * 8);
        gload_lds16(gp, &vT_lds[(i * 256 + w * 64) * 8]);
      }
      __syncthreads();

      f32x4 sfr[4];
#pragma unroll
      for (int js = 0; js < 4; ++js) sfr[js] = 0.f;
#pragma unroll
      for (int js = 0; js < 4; ++js) {
        int row = js * 16 + lc;
#pragma unroll
        for (int db = 0; db < 4; ++db) {
          s16x8 kf = *(const s16x8*)&k_lds[row * 128 + (((db * 4 + lg) ^ (lc & 7)) * 8)];
          sfr[js] = __builtin_amdgcn_mfma_f32_16x16x32_bf16(qfrag[db], kf, sfr[js], 0, 0, 0);
        }
      }
      float eb[4];
#pragma unroll
      for (int js = 0; js < 4; ++js) eb[js] = ebias[hk * S_ + j0 + js * 16 + lc];

      const bool diag = (tj == qb);
      float sclv[4];
#pragma unroll
      for (int r = 0; r < 4; ++r) {
        float sv[4];
#pragma unroll
        for (int js = 0; js < 4; ++js) sv[js] = sfr[js][r] * SCALE_ + eb[js];
        if (diag) {
          int qrow = w * 16 + lg * 4 + r;
#pragma unroll
          for (int js = 0; js < 4; ++js)
            if (js * 16 + lc > qrow) sv[js] = -INFINITY;
        }
        float tm = fmaxf(fmaxf(sv[0], sv[1]), fmaxf(sv[2], sv[3]));
#pragma unroll
        for (int off = 1; off < 16; off <<= 1) tm = fmaxf(tm, __shfl_xor(tm, off, 64));
        float mnew = fmaxf(mr[r], tm);
        float scl = __expf(mr[r] - mnew);
        float ps = 0.f;
#pragma unroll
        for (int js = 0; js < 4; ++js) {
          float e = __expf(sv[js] - mnew);
          s_lds[w][lg * 4 + r][js * 16 + lc] = e;
          ps += e;
        }
#pragma unroll
        for (int off = 1; off < 16; off <<= 1) ps += __shfl_xor(ps, off, 64);
        lr[r] = lr[r] * scl + ps;
        mr[r] = mnew;
        sclv[r] = scl;
      }
#pragma unroll
      for (int n = 0; n < 8; ++n) {
        f32x4 ov = o[n];
#pragma unroll
        for (int r = 0; r < 4; ++r) ov[r] *= sclv[r];
        o[n] = ov;
      }
      asm volatile("s_waitcnt lgkmcnt(0)" ::: "memory");
      s16x8 pa[2];
#pragma unroll
      for (int ks = 0; ks < 2; ++ks) {
        float pv[8];
        *(f32x4*)&pv[0] = *(const f32x4*)&s_lds[w][lc][ks * 32 + lg * 8];
        *(f32x4*)&pv[4] = *(const f32x4*)&s_lds[w][lc][ks * 32 + lg * 8 + 4];
        s16x8 pk;
#pragma unroll
        for (int e = 0; e < 8; ++e) pk[e] = (short)f2bf(pv[e]);
        pa[ks] = pk;
      }
#pragma unroll
      for (int n = 0; n < 8; ++n) {
        int d = n * 16 + lc;
#pragma unroll
        for (int ks = 0; ks < 2; ++ks) {
          s16x8 vf = *(const s16x8*)&vT_lds[d * 64 + (((ks * 4 + lg) ^ (lc & 7)) * 8)];
          o[n] = __builtin_amdgcn_mfma_f32_16x16x32_bf16(pa[ks], vf, o[n], 0, 0, 0);
        }
      }
    }
#pragma unroll
    for (int r = 0; r < 4; ++r) {
      float rinv = 1.0f / lr[r];
      int row = q0 + lg * 4 + r;
#pragma unroll
      for (int n = 0; n < 8; ++n)
        ob16[(size_t)row * NQ_ + h * D_ + n * 16 + lc] = f2bf(o[n][r] * rinv);
    }
  }
}

// ---------------- launcher ----------------
extern "C" void kernel_launch(void* const* d_in, const int* in_sizes, int n_in,
                              void* d_out, int out_size, void* d_ws, size_t ws_size,
                              hipStream_t stream) {
  (void)in_sizes; (void)n_in; (void)out_size; (void)ws_size;
  const float* hid = (const float*)d_in[0];
  const float* wq  = (const float*)d_in[1];
  const float* wk  = (const float*)d_in[2];
  const float* wv  = (const float*)d_in[3];
  const float* wo  = (const float*)d_in[4];
  float* out = (float*)d_out;
  char* ws = (char*)d_ws;
  const size_t MB = 1ull << 20;

  // Phase-ordered overlay map (alive intervals verified against launch order):
  ushort_t* h0     = (ushort_t*)(ws + 0 * MB);     // A -> C
  ushort_t* h1     = (ushort_t*)(ws + 16 * MB);    // A -> B/D
  ushort_t* h2     = (ushort_t*)(ws + 32 * MB);    // A -> B/D
  ushort_t* wq0T   = (ushort_t*)(ws + 48 * MB);    // A -> C
  ushort_t* wq1T   = (ushort_t*)(ws + 80 * MB);    // A -> D
  ushort_t* wq2T   = (ushort_t*)(ws + 112 * MB);   // A -> D
  ushort_t* wkv0T  = (ushort_t*)(ws + 144 * MB);   // A -> B
  ushort_t* wkv1T  = (ushort_t*)(ws + 160 * MB);   // A -> B
  ushort_t* wkv2T  = (ushort_t*)(ws + 176 * MB);   // A -> B
  float*    qpart  = (float*)(ws + 192 * MB);      // D only (16 MB)
  float*    qobs   = (float*)(ws + 208 * MB);      // D -> G (2 MB)
  float*    kvf    = (float*)(ws + 210 * MB);      // B -> I (16 MB)
  float*    qf     = (float*)(ws + 80 * MB);       // C -> F (over dead wq1T)
  ushort_t* qb16   = (ushort_t*)(ws + 112 * MB);   // F -> I (over dead wq2T)
  float*    s_obs  = (float*)(ws + 0 * MB);        // G (32 MB, over dead h0/h1)
  ushort_t* woT    = (ushort_t*)(ws + 144 * MB);   // E -> I (over dead wkv0T/1T)
  ushort_t* ksp    = (ushort_t*)(ws + 176 * MB);   // I (over dead wkv2T)
  ushort_t* vsp    = (ushort_t*)(ws + 180 * MB);
  ushort_t* vspT   = (ushort_t*)(ws + 184 * MB);
  ushort_t* ob16   = (ushort_t*)(ws + 188 * MB);   // I (over dead qpart)
  ushort_t* qo0    = (ushort_t*)(ws + 32 * MB);    // G (over dead h2)
  ushort_t* qo1    = (ushort_t*)(ws + 33 * MB);
  ushort_t* qo2    = (ushort_t*)(ws + 34 * MB);
  ushort_t* kb0    = (ushort_t*)(ws + 35 * MB);
  ushort_t* kb1    = (ushort_t*)(ws + 39 * MB);
  ushort_t* kb2    = (ushort_t*)(ws + 43 * MB);
  char*     misc   = ws + 226 * MB;
  float*    impv   = (float*)(misc + 0);
  float*    eb     = (float*)(misc + 64 * 1024);
  float*    invf   = (float*)(misc + 128 * 1024);
  float*    thr    = (float*)(misc + 132 * 1024);
  unsigned* prefix = (unsigned*)(misc + 136 * 1024);
  unsigned* kneed  = (unsigned*)(misc + 140 * 1024);
  unsigned* hist   = (unsigned*)(misc + 144 * 1024);
  float*    mxbuf  = (float*)(misc + 160 * 1024);
  float*    dinvb  = (float*)(misc + 176 * 1024);
  float*    part   = (float*)(misc + 256 * 1024);  // 512 KB

  // A) splits
  split3_kernel<<<(S_ * HID_ / 4 + 255) / 256, 256, 0, stream>>>(hid, h0, h1, h2, S_ * HID_ / 4);
  splitT_kernel<<<dim3(NQ_ / 64, HID_ / 64), 256, 0, stream>>>(wq, NQ_, wq0T, wq1T, wq2T);
  splitT_kernel<<<dim3(NKV_ / 64, HID_ / 64), 256, 0, stream>>>(wk, NKV_, wkv0T, wkv1T, wkv2T);
  splitT_kernel<<<dim3(NKV_ / 64, HID_ / 64), 256, 0, stream>>>(
      wv, NKV_, wkv0T + (size_t)NKV_ * HID_, wkv1T + (size_t)NKV_ * HID_, wkv2T + (size_t)NKV_ * HID_);

  // D) obs-Q 6-product bf16, K-sliced (z=8 x 512), then fixed-order reduce
  const size_t obs_off = (size_t)(S_ - OBS_) * HID_;
  gemm_btk<1><<<dim3(NQ_ / 128, 1, 8), 256, 0, stream>>>(h0 + obs_off, h1 + obs_off, wq0T, wq1T, qpart, NQ_);
  gemm_btk<2><<<dim3(NQ_ / 128, 1, 8), 256, 0, stream>>>(h0 + obs_off, h2 + obs_off, wq0T, wq2T, qpart, NQ_);
  reduce8_kernel<<<(OBS_ * NQ_ + 255) / 256, 256, 0, stream>>>(qpart, qobs, OBS_ * NQ_);

  // B) K|V 6-product bf16 (fp32-grade)
  gemm_bt<1><<<dim3(2048 / 128, S_ / 128), 256, 0, stream>>>(h0, h1, wkv0T, wkv1T, kvf, S_, 2048, HID_);
  gemm_bt<2><<<dim3(2048 / 128, S_ / 128), 256, 0, stream>>>(h0, h2, wkv0T, wkv2T, kvf, S_, 2048, HID_);

  // C) Q main GEMM (bf16 path)
  gemm_bt<0><<<dim3(NQ_ / 128, S_ / 128), 256, 0, stream>>>(h0, nullptr, wq0T, nullptr, qf, S_, NQ_, HID_);

  // E) wo transpose+cast
  splitT_kernel<<<dim3(HID_ / 64, HID_ / 64), 256, 0, stream>>>(wo, HID_, woT, nullptr, nullptr);

  // F) RoPE
  freq_kernel<<<1, 64, 0, stream>>>(invf);
  rope_kernel<<<(S_ * HQ_ * 64 + 255) / 256, 256, 0, stream>>>(qf, qb16, invf, HQ_, NQ_, 0, S_ * HQ_ * 64);
  rope_kernel<<<(S_ * HKV_ * 64 + 255) / 256, 256, 0, stream>>>(kvf, nullptr, invf, HKV_, KLD_, 0, S_ * HKV_ * 64);
  rope_kernel<<<(OBS_ * HQ_ * 64 + 255) / 256, 256, 0, stream>>>(qobs, nullptr, invf, HQ_, NQ_, S_ - OBS_, OBS_ * HQ_ * 64);

  // G) obs importance via MFMA GEMM + parallel reductions
  splitq_obs<<<(OBS_ * NQ_ / 4 + 255) / 256, 256, 0, stream>>>(qobs, qo0, qo1, qo2);
  splitk_obs<<<(S_ * NKV_ / 4 + 255) / 256, 256, 0, stream>>>(kvf, kb0, kb1, kb2);
  gemm_btz<1><<<dim3(16, 4, 8), 256, 0, stream>>>(qo0, qo1, kb0, kb1, s_obs, 512, S_, D_);
  gemm_btz<2><<<dim3(16, 4, 8), 256, 0, stream>>>(qo0, qo2, kb0, kb2, s_obs, 512, S_, D_);
  rowstat_kernel<<<1024, 256, 0, stream>>>(s_obs, mxbuf, dinvb);
  colsum_part<<<dim3(8, 8, 8), 256, 0, stream>>>(s_obs, mxbuf, dinvb, part);
  colsum_fin<<<64, 256, 0, stream>>>(part, impv);

  // H) quantile thresholds
  radix_init<<<1, 64, 0, stream>>>(prefix, kneed);
  for (int pass = 0; pass < 4; ++pass) {
    hipMemsetAsync(hist, 0, 4096, stream);
    radix_hist<<<(NC_ + 255) / 256, 256, 0, stream>>>(impv, prefix, pass, hist);
    radix_scan<<<1, 64, 0, stream>>>(hist, prefix, kneed, pass, thr);
  }

  // I) sparsify + V-transpose + attention + out projection
  sparsify_kernel<<<S_ * HKV_, 128, 0, stream>>>(kvf, impv, thr, ksp, vsp, eb);
  vtrans_kernel<<<dim3(S_ / 64, HKV_), 256, 0, stream>>>(vsp, vspT);
  attn_kernel<<<512, 256, 0, stream>>>(qb16, ksp, vspT, eb, ob16);
  gemm_bt<0><<<dim3(HID_ / 128, S_ / 128), 256, 0, stream>>>(ob16, nullptr, woT, nullptr, out, S_, HID_, HID_);
}

// Round 6
// 973.670 us; speedup vs baseline: 1.1394x; 1.0358x over previous
//
#include <hip/hip_runtime.h>
#include <hip/hip_bf16.h>
#include <math.h>

#define S_    2048
#define HID_  4096
#define HQ_   32
#define HKV_  8
#define D_    128
#define G_    4
#define OBS_  128
#define W_    32
#define NKV_  1024
#define NQ_   4096
#define KLD_  2048
#define SCALE_ 0.08838834764831845f
#define THR_IDX_ 89
#define NC_   16128

typedef __attribute__((ext_vector_type(4))) float f32x4;
typedef __attribute__((ext_vector_type(8))) short s16x8;
typedef __attribute__((ext_vector_type(8))) unsigned short u16x8;
typedef __attribute__((ext_vector_type(4))) unsigned short u16x4;
typedef unsigned short ushort_t;

struct TermPtrs { const ushort_t* a[6]; const ushort_t* b[6]; };

__device__ __forceinline__ unsigned short f2bf(float x) {
  union { float f; unsigned u; } v; v.f = x;
  unsigned r = v.u + 0x7FFFu + ((v.u >> 16) & 1u);
  return (unsigned short)(r >> 16);
}
__device__ __forceinline__ float bf2f(unsigned short b) {
  union { unsigned u; float f; } v; v.u = ((unsigned)b) << 16;
  return v.f;
}
__device__ __forceinline__ void gload_lds16(const void* g, void* l) {
  __builtin_amdgcn_global_load_lds((const __attribute__((address_space(1))) unsigned int*)g,
                                   (__attribute__((address_space(3))) unsigned int*)l, 16, 0, 0);
}
__device__ __forceinline__ void term_sel(const TermPtrs& P, int tt,
                                         const ushort_t*& As, const ushort_t*& Bs) {
  switch (tt) {
    case 0: As = P.a[0]; Bs = P.b[0]; break;
    case 1: As = P.a[1]; Bs = P.b[1]; break;
    case 2: As = P.a[2]; Bs = P.b[2]; break;
    case 3: As = P.a[3]; Bs = P.b[3]; break;
    case 4: As = P.a[4]; Bs = P.b[4]; break;
    default: As = P.a[5]; Bs = P.b[5]; break;
  }
}

// ---------------- split fp32 -> 3 bf16 terms ----------------
__global__ __launch_bounds__(256) void split3_kernel(const float* __restrict__ src,
                                                     ushort_t* __restrict__ d0,
                                                     ushort_t* __restrict__ d1,
                                                     ushort_t* __restrict__ d2, int n4) {
  int idx = blockIdx.x * 256 + threadIdx.x;
  if (idx >= n4) return;
  float4 v = ((const float4*)src)[idx];
  u16x4 o0, o1, o2;
  float xs[4] = {v.x, v.y, v.z, v.w};
#pragma unroll
  for (int e = 0; e < 4; ++e) {
    float x = xs[e];
    unsigned short b0 = f2bf(x);
    float r = x - bf2f(b0);
    unsigned short b1 = f2bf(r);
    float r2 = r - bf2f(b1);
    o0[e] = b0; o1[e] = b1; o2[e] = f2bf(r2);
  }
  *(u16x4*)(d0 + (size_t)idx * 4) = o0;
  *(u16x4*)(d1 + (size_t)idx * 4) = o1;
  *(u16x4*)(d2 + (size_t)idx * 4) = o2;
}

// ---------------- split + transpose weights ----------------
__global__ __launch_bounds__(256) void splitT_kernel(const float* __restrict__ src, int N,
                                                     ushort_t* __restrict__ t0,
                                                     ushort_t* __restrict__ t1,
                                                     ushort_t* __restrict__ t2) {
  __shared__ float tile[64][65];
  const int t = threadIdx.x;
  const int n0 = blockIdx.x * 64, k0 = blockIdx.y * 64;
#pragma unroll
  for (int i = 0; i < 16; ++i) {
    int idx = i * 256 + t;
    int r = idx >> 6, c = idx & 63;
    tile[r][c] = src[(size_t)(k0 + r) * N + n0 + c];
  }
  __syncthreads();
#pragma unroll
  for (int i = 0; i < 16; ++i) {
    int idx = i * 256 + t;
    int n = idx >> 6, kk = idx & 63;
    float x = tile[kk][n];
    unsigned short b0 = f2bf(x);
    size_t o = (size_t)(n0 + n) * HID_ + k0 + kk;
    t0[o] = b0;
    if (t1) {
      float r = x - bf2f(b0);
      unsigned short b1 = f2bf(r);
      t1[o] = b1;
      t2[o] = f2bf(r - bf2f(b1));
    }
  }
}

// ---------------- unified virtual-K bf16 MFMA GEMM (TPZ terms per grid.z) ----------------
// A rows: M x K (row stride K), B rows: N x K. C partial per z: z*M*N offset.
template<int TPZ>
__global__ __launch_bounds__(256) void gemm6(TermPtrs P, float* __restrict__ Cbase,
                                             int M, int N, int K) {
  __shared__ ushort_t lds[2 * 128 * 64];
  const int t = threadIdx.x;
  const int wave = t >> 6, lane = t & 63;
  const int lc = lane & 15, lg = lane >> 4;
  const int bm = blockIdx.y, bn = blockIdx.x, z = blockIdx.z;
  const int wm = wave >> 1, wn = wave & 1;
  const int srow = t >> 3, schunk = t & 7;
  float* C = Cbase + (size_t)z * M * N;

  f32x4 acc[4][4];
#pragma unroll
  for (int fi = 0; fi < 4; ++fi)
#pragma unroll
    for (int fj = 0; fj < 4; ++fj) acc[fi][fj] = 0.f;

  for (int tt = z * TPZ; tt < z * TPZ + TPZ; ++tt) {
    const ushort_t *As, *Bs;
    term_sel(P, tt, As, Bs);
    for (int kb = 0; kb < K / 64; ++kb) {
      __syncthreads();
#pragma unroll
      for (int g = 0; g < 4; ++g) {
        int row = g * 32 + srow;
        int sw = schunk ^ (row & 7);
        gload_lds16(As + (size_t)(bm * 128 + row) * K + kb * 64 + sw * 8,
                    lds + g * 2048 + wave * 512);
        gload_lds16(Bs + (size_t)(bn * 128 + row) * K + kb * 64 + sw * 8,
                    lds + 8192 + g * 2048 + wave * 512);
      }
      __syncthreads();
#pragma unroll
      for (int ks = 0; ks < 2; ++ks) {
        s16x8 af[4], bf[4];
#pragma unroll
        for (int f = 0; f < 4; ++f) {
          int ra = wm * 64 + f * 16 + lc;
          af[f] = *(const s16x8*)(lds + ra * 64 + (((ks * 4 + lg) ^ (ra & 7)) * 8));
          int rb = wn * 64 + f * 16 + lc;
          bf[f] = *(const s16x8*)(lds + 8192 + rb * 64 + (((ks * 4 + lg) ^ (rb & 7)) * 8));
        }
#pragma unroll
        for (int fi = 0; fi < 4; ++fi)
#pragma unroll
          for (int fj = 0; fj < 4; ++fj)
            acc[fi][fj] = __builtin_amdgcn_mfma_f32_16x16x32_bf16(af[fi], bf[fj], acc[fi][fj], 0, 0, 0);
      }
    }
  }
#pragma unroll
  for (int fi = 0; fi < 4; ++fi)
#pragma unroll
    for (int fj = 0; fj < 4; ++fj)
#pragma unroll
      for (int r = 0; r < 4; ++r)
        C[(size_t)(bm * 128 + wm * 64 + fi * 16 + lg * 4 + r) * N +
          bn * 128 + wn * 64 + fj * 16 + lc] = acc[fi][fj][r];
}

// ---------------- obs-Q: M=128, all 6 terms, z = K-slice of 512 ----------------
__global__ __launch_bounds__(256) void gemm6k(TermPtrs P, float* __restrict__ Cp, int N) {
  __shared__ ushort_t lds[2 * 128 * 64];
  const int t = threadIdx.x;
  const int wave = t >> 6, lane = t & 63;
  const int lc = lane & 15, lg = lane >> 4;
  const int bn = blockIdx.x, z = blockIdx.z;
  const int wm = wave >> 1, wn = wave & 1;
  const int srow = t >> 3, schunk = t & 7;
  float* C = Cp + (size_t)z * 128 * N;

  f32x4 acc[4][4];
#pragma unroll
  for (int fi = 0; fi < 4; ++fi)
#pragma unroll
    for (int fj = 0; fj < 4; ++fj) acc[fi][fj] = 0.f;

  for (int tt = 0; tt < 6; ++tt) {
    const ushort_t *As, *Bs;
    term_sel(P, tt, As, Bs);
    for (int kb = z * 8; kb < z * 8 + 8; ++kb) {
      __syncthreads();
#pragma unroll
      for (int g = 0; g < 4; ++g) {
        int row = g * 32 + srow;
        int sw = schunk ^ (row & 7);
        gload_lds16(As + (size_t)row * HID_ + kb * 64 + sw * 8,
                    lds + g * 2048 + wave * 512);
        gload_lds16(Bs + (size_t)(bn * 128 + row) * HID_ + kb * 64 + sw * 8,
                    lds + 8192 + g * 2048 + wave * 512);
      }
      __syncthreads();
#pragma unroll
      for (int ks = 0; ks < 2; ++ks) {
        s16x8 af[4], bf[4];
#pragma unroll
        for (int f = 0; f < 4; ++f) {
          int ra = wm * 64 + f * 16 + lc;
          af[f] = *(const s16x8*)(lds + ra * 64 + (((ks * 4 + lg) ^ (ra & 7)) * 8));
          int rb = wn * 64 + f * 16 + lc;
          bf[f] = *(const s16x8*)(lds + 8192 + rb * 64 + (((ks * 4 + lg) ^ (rb & 7)) * 8));
        }
#pragma unroll
        for (int fi = 0; fi < 4; ++fi)
#pragma unroll
          for (int fj = 0; fj < 4; ++fj)
            acc[fi][fj] = __builtin_amdgcn_mfma_f32_16x16x32_bf16(af[fi], bf[fj], acc[fi][fj], 0, 0, 0);
      }
    }
  }
#pragma unroll
  for (int fi = 0; fi < 4; ++fi)
#pragma unroll
    for (int fj = 0; fj < 4; ++fj)
#pragma unroll
      for (int r = 0; r < 4; ++r)
        C[(size_t)(wm * 64 + fi * 16 + lg * 4 + r) * N +
          bn * 128 + wn * 64 + fj * 16 + lc] = acc[fi][fj][r];
}

// ---------------- s_obs: all 6 terms, z = kv-head (data offset), K=128 ----------------
__global__ __launch_bounds__(256) void gemm6z(TermPtrs P, float* __restrict__ Cg) {
  __shared__ ushort_t lds[2 * 128 * 64];
  const int t = threadIdx.x;
  const int wave = t >> 6, lane = t & 63;
  const int lc = lane & 15, lg = lane >> 4;
  const int bm = blockIdx.y, bn = blockIdx.x, z = blockIdx.z;
  const int wm = wave >> 1, wn = wave & 1;
  const int srow = t >> 3, schunk = t & 7;
  const size_t Aoff = (size_t)z * 512 * 128;
  const size_t Boff = (size_t)z * 2048 * 128;
  float* C = Cg + (size_t)z * 512 * 2048;

  f32x4 acc[4][4];
#pragma unroll
  for (int fi = 0; fi < 4; ++fi)
#pragma unroll
    for (int fj = 0; fj < 4; ++fj) acc[fi][fj] = 0.f;

  for (int tt = 0; tt < 6; ++tt) {
    const ushort_t *As, *Bs;
    term_sel(P, tt, As, Bs);
    As += Aoff; Bs += Boff;
    for (int kb = 0; kb < 2; ++kb) {
      __syncthreads();
#pragma unroll
      for (int g = 0; g < 4; ++g) {
        int row = g * 32 + srow;
        int sw = schunk ^ (row & 7);
        gload_lds16(As + (size_t)(bm * 128 + row) * 128 + kb * 64 + sw * 8,
                    lds + g * 2048 + wave * 512);
        gload_lds16(Bs + (size_t)(bn * 128 + row) * 128 + kb * 64 + sw * 8,
                    lds + 8192 + g * 2048 + wave * 512);
      }
      __syncthreads();
#pragma unroll
      for (int ks = 0; ks < 2; ++ks) {
        s16x8 af[4], bf[4];
#pragma unroll
        for (int f = 0; f < 4; ++f) {
          int ra = wm * 64 + f * 16 + lc;
          af[f] = *(const s16x8*)(lds + ra * 64 + (((ks * 4 + lg) ^ (ra & 7)) * 8));
          int rb = wn * 64 + f * 16 + lc;
          bf[f] = *(const s16x8*)(lds + 8192 + rb * 64 + (((ks * 4 + lg) ^ (rb & 7)) * 8));
        }
#pragma unroll
        for (int fi = 0; fi < 4; ++fi)
#pragma unroll
          for (int fj = 0; fj < 4; ++fj)
            acc[fi][fj] = __builtin_amdgcn_mfma_f32_16x16x32_bf16(af[fi], bf[fj], acc[fi][fj], 0, 0, 0);
      }
    }
  }
#pragma unroll
  for (int fi = 0; fi < 4; ++fi)
#pragma unroll
    for (int fj = 0; fj < 4; ++fj)
#pragma unroll
      for (int r = 0; r < 4; ++r)
        C[(size_t)(bm * 128 + wm * 64 + fi * 16 + lg * 4 + r) * 2048 +
          bn * 128 + wn * 64 + fj * 16 + lc] = acc[fi][fj][r];
}

// ---------------- partial reductions ----------------
__global__ void reduce3_kernel(const float* __restrict__ p, float* __restrict__ out, int n4) {
  int idx = blockIdx.x * 256 + threadIdx.x;
  if (idx >= n4) return;
  const size_t n = (size_t)n4 * 4;
  float4 a = ((const float4*)p)[idx];
  float4 b = ((const float4*)(p + n))[idx];
  float4 c = ((const float4*)(p + 2 * n))[idx];
  float4 o;
  o.x = a.x + b.x + c.x; o.y = a.y + b.y + c.y;
  o.z = a.z + b.z + c.z; o.w = a.w + b.w + c.w;
  ((float4*)out)[idx] = o;
}
__global__ void reduce8_kernel(const float* __restrict__ Cp, float* __restrict__ out, int n) {
  int idx = blockIdx.x * 256 + threadIdx.x;
  if (idx >= n) return;
  float s = 0.f;
#pragma unroll
  for (int z = 0; z < 8; ++z) s += Cp[(size_t)z * n + idx];
  out[idx] = s;
}

// ---------------- inv_freq ----------------
__global__ void freq_kernel(float* __restrict__ invf) {
  int j = threadIdx.x;
  if (j < 64) invf[j] = (float)(1.0 / pow(500000.0, (double)j / 64.0));
}

// ---------------- RoPE ----------------
__global__ void rope_kernel(float* __restrict__ X, ushort_t* __restrict__ Xb,
                            const float* __restrict__ invf, int H, int ld, int pos0, int total) {
  int idx = blockIdx.x * 256 + threadIdx.x;
  if (idx >= total) return;
  int j = idx & 63;
  int h = (idx >> 6) % H;
  int s = idx / (64 * H);
  float ang = (float)(pos0 + s) * invf[j];
  float sn, cs;
  sincosf(ang, &sn, &cs);
  size_t base = (size_t)s * ld + h * D_ + j;
  float x1 = X[base], x2 = X[base + 64];
  float o1 = x1 * cs - x2 * sn;
  float o2 = x2 * cs + x1 * sn;
  X[base] = o1; X[base + 64] = o2;
  if (Xb) { Xb[base] = f2bf(o1); Xb[base + 64] = f2bf(o2); }
}

// ---------------- obs-Q 3-split into [hk][g*128+i][d] ----------------
__global__ __launch_bounds__(256) void splitq_obs(const float* __restrict__ qobs,
                                                  ushort_t* __restrict__ q0,
                                                  ushort_t* __restrict__ q1,
                                                  ushort_t* __restrict__ q2) {
  int idx = blockIdx.x * 256 + threadIdx.x;
  if (idx >= OBS_ * NQ_ / 4) return;
  int idx4 = idx * 4;
  int i = idx4 >> 12;
  int col = idx4 & 4095;
  int hq = col >> 7, d = col & 127;
  int hk = hq >> 2, g = hq & 3;
  float4 v = *(const float4*)(qobs + (size_t)i * NQ_ + col);
  size_t o = (size_t)hk * 65536 + (size_t)(g * 128 + i) * 128 + d;
  float xs[4] = {v.x, v.y, v.z, v.w};
  u16x4 o0, o1, o2;
#pragma unroll
  for (int e = 0; e < 4; ++e) {
    float x = xs[e];
    unsigned short b0 = f2bf(x);
    float r = x - bf2f(b0);
    unsigned short b1 = f2bf(r);
    o0[e] = b0; o1[e] = b1; o2[e] = f2bf(r - bf2f(b1));
  }
  *(u16x4*)(q0 + o) = o0;
  *(u16x4*)(q1 + o) = o1;
  *(u16x4*)(q2 + o) = o2;
}

// ---------------- K 3-split into [hk][j][d] ----------------
__global__ __launch_bounds__(256) void splitk_obs(const float* __restrict__ kvf,
                                                  ushort_t* __restrict__ k0,
                                                  ushort_t* __restrict__ k1,
                                                  ushort_t* __restrict__ k2) {
  int idx = blockIdx.x * 256 + threadIdx.x;
  if (idx >= S_ * NKV_ / 4) return;
  int idx4 = idx * 4;
  int j = idx4 >> 10;
  int col = idx4 & 1023;
  int hk = col >> 7, d = col & 127;
  float4 v = *(const float4*)(kvf + (size_t)j * KLD_ + col);
  size_t o = (size_t)hk * 262144 + ((size_t)j << 7) + d;
  float xs[4] = {v.x, v.y, v.z, v.w};
  u16x4 o0, o1, o2;
#pragma unroll
  for (int e = 0; e < 4; ++e) {
    float x = xs[e];
    unsigned short b0 = f2bf(x);
    float r = x - bf2f(b0);
    unsigned short b1 = f2bf(r);
    o0[e] = b0; o1[e] = b1; o2[e] = f2bf(r - bf2f(b1));
  }
  *(u16x4*)(k0 + o) = o0;
  *(u16x4*)(k1 + o) = o1;
  *(u16x4*)(k2 + o) = o2;
}

// ---------------- per-row max + inv-denominator (causal) ----------------
__global__ __launch_bounds__(256) void rowstat_kernel(const float* __restrict__ s,
                                                      float* __restrict__ mx,
                                                      float* __restrict__ dinv) {
  const int row = blockIdx.x * 4 + (threadIdx.x >> 6);
  const int lane = threadIdx.x & 63;
  const int i = row & 127;
  const int jmax = S_ - OBS_ + i;
  const float* sp = s + (size_t)row * S_;
  float vals[32];
  float m = -INFINITY;
#pragma unroll
  for (int c = 0; c < 8; ++c) {
    int j0 = c * 256 + lane * 4;
    float4 v = *(const float4*)(sp + j0);
    float e0 = (j0 + 0 <= jmax) ? v.x * SCALE_ : -INFINITY;
    float e1 = (j0 + 1 <= jmax) ? v.y * SCALE_ : -INFINITY;
    float e2 = (j0 + 2 <= jmax) ? v.z * SCALE_ : -INFINITY;
    float e3 = (j0 + 3 <= jmax) ? v.w * SCALE_ : -INFINITY;
    vals[c * 4 + 0] = e0; vals[c * 4 + 1] = e1; vals[c * 4 + 2] = e2; vals[c * 4 + 3] = e3;
    m = fmaxf(m, fmaxf(fmaxf(e0, e1), fmaxf(e2, e3)));
  }
#pragma unroll
  for (int off = 1; off < 64; off <<= 1) m = fmaxf(m, __shfl_xor(m, off, 64));
  float ssum = 0.f;
#pragma unroll
  for (int c = 0; c < 32; ++c) ssum += expf(vals[c] - m);
#pragma unroll
  for (int off = 1; off < 64; off <<= 1) ssum += __shfl_xor(ssum, off, 64);
  if (lane == 0) { mx[row] = m; dinv[row] = 1.0f / ssum; }
}

// ---------------- column-sum stage 1: 64-row chunks ----------------
__global__ __launch_bounds__(256) void colsum_part(const float* __restrict__ s,
                                                   const float* __restrict__ mx,
                                                   const float* __restrict__ dinv,
                                                   float* __restrict__ part) {
  __shared__ float mxl[64], dvl[64];
  const int jt = blockIdx.x, hk = blockIdx.y, rc = blockIdx.z;
  const int t = threadIdx.x;
  if (t < 64) {
    mxl[t] = mx[hk * 512 + rc * 64 + t];
    dvl[t] = dinv[hk * 512 + rc * 64 + t];
  }
  __syncthreads();
  const int j = jt * 256 + t;
  const float* sp = s + ((size_t)hk * 512 + rc * 64) * S_ + j;
  float acc = 0.f;
  for (int rr = 0; rr < 64; ++rr) {
    int i = (rc * 64 + rr) & 127;
    if (j <= S_ - OBS_ + i)
      acc += expf(sp[(size_t)rr * S_] * SCALE_ - mxl[rr]) * dvl[rr];
  }
  part[((size_t)rc * 8 + hk) * S_ + j] = acc;
}

// ---------------- column-sum stage 2 -> imp ----------------
__global__ void colsum_fin(const float* __restrict__ part, float* __restrict__ imp) {
  int idx = blockIdx.x * 256 + threadIdx.x;
  int hk = idx >> 11, j = idx & 2047;
  float acc = 0.f;
#pragma unroll
  for (int rc = 0; rc < 8; ++rc) acc += part[((size_t)rc * 8 + hk) * S_ + j];
  float cnt = (float)min(OBS_, S_ - j);
  imp[idx] = acc * 0.25f / cnt;
}

// ---------------- single-block radix select for both quantiles ----------------
__global__ __launch_bounds__(1024) void radix_all(const float* __restrict__ imp,
                                                  float* __restrict__ thr) {
  __shared__ unsigned hist[4][256];
  __shared__ unsigned pfx_s[4], need_s[4];
  const int t = threadIdx.x;
  if (t < 4) {
    pfx_s[t] = 0u;
    need_s[t] = (t == 0) ? 3225u : (t == 1) ? 3226u : (t == 2) ? 15320u : 15321u;
  }
  __syncthreads();
  for (int pass = 0; pass < 4; ++pass) {
    ((unsigned*)hist)[t] = 0u;
    __syncthreads();
    int shift = 24 - pass * 8;
    for (int idx = t; idx < NC_; idx += 1024) {
      int h = idx / (S_ - W_), j = idx - h * (S_ - W_);
      union { float f; unsigned u; } cv; cv.f = imp[h * S_ + j];
      unsigned u = cv.u;
#pragma unroll
      for (int q = 0; q < 4; ++q) {
        bool m = (pass == 0) || ((u >> (shift + 8)) == (pfx_s[q] >> (shift + 8)));
        if (m) atomicAdd(&hist[q][(u >> shift) & 255u], 1u);
      }
    }
    __syncthreads();
    if (t < 4) {
      unsigned need = need_s[t], cum = 0, pfx = pfx_s[t];
      for (int d = 0; d < 256; ++d) {
        unsigned c = hist[t][d];
        if (cum + c > need) { pfx |= ((unsigned)d) << shift; need_s[t] = need - cum; break; }
        cum += c;
      }
      pfx_s[t] = pfx;
    }
    __syncthreads();
  }
  if (t == 0) {
    union { unsigned u; float f; } c0, c1, c2, c3;
    c0.u = pfx_s[0]; c1.u = pfx_s[1]; c2.u = pfx_s[2]; c3.u = pfx_s[3];
    double fl = 0.2 * (double)(NC_ - 1) - 3225.0;
    double fh = 0.95 * (double)(NC_ - 1) - 15320.0;
    thr[0] = (float)((double)c2.f + ((double)c3.f - (double)c2.f) * fh);
    thr[1] = (float)((double)c0.f + ((double)c1.f - (double)c0.f) * fl);
  }
}

// ---------------- sparsify ----------------
__global__ __launch_bounds__(128) void sparsify_kernel(const float* __restrict__ kv,
                                                       const float* __restrict__ imp,
                                                       const float* __restrict__ thr,
                                                       ushort_t* __restrict__ ksp,
                                                       ushort_t* __restrict__ vsp,
                                                       float* __restrict__ ebias) {
  const int b = blockIdx.x;
  const int j = b >> 3;
  const int h = b & 7;
  const int t = threadIdx.x;
  float ipv = imp[h * S_ + j];
  bool dense = (j >= S_ - W_) || (j < 2);
  int lvl = dense ? 0 : ((ipv >= thr[0]) ? 0 : ((ipv < thr[1]) ? 2 : 1));
  if (t == 0) ebias[h * S_ + j] = (lvl == 2) ? -INFINITY : 0.0f;
  __shared__ float av[128];
  __shared__ float thv;
  size_t base_in = (size_t)j * KLD_ + h * D_;
  size_t base_out = (size_t)j * NKV_ + h * D_;
  float kvv = kv[base_in + t];
  av[t] = fabsf(kvv);
  __syncthreads();
  {
    float at = av[t]; int cnt = 0;
    for (int m = 0; m < 128; ++m) { float am = av[m]; cnt += (am < at) || (am == at && m < t); }
    if (cnt == THR_IDX_) thv = at;
  }
  __syncthreads();
  {
    bool keep = (lvl == 0) || (lvl == 1 && fabsf(kvv) >= thv);
    ksp[base_out + t] = f2bf(keep ? kvv : 0.0f);
  }
  __syncthreads();
  float vvv = kv[base_in + 1024 + t];
  av[t] = fabsf(vvv);
  __syncthreads();
  {
    float at = av[t]; int cnt = 0;
    for (int m = 0; m < 128; ++m) { float am = av[m]; cnt += (am < at) || (am == at && m < t); }
    if (cnt == THR_IDX_) thv = at;
  }
  __syncthreads();
  {
    bool keep = (lvl == 0) || (lvl == 1 && fabsf(vvv) >= thv);
    vsp[base_out + t] = f2bf(keep ? vvv : 0.0f);
  }
}

// ---------------- V transpose ----------------
__global__ __launch_bounds__(256) void vtrans_kernel(const ushort_t* __restrict__ vsp,
                                                     ushort_t* __restrict__ vspT) {
  __shared__ ushort_t tl[64][136];
  const int jt = blockIdx.x;
  const int hk = blockIdx.y;
  const int t = threadIdx.x;
#pragma unroll
  for (int i = 0; i < 4; ++i) {
    int idx = i * 256 + t;
    int j = idx >> 4, c = idx & 15;
    *(u16x8*)&tl[j][c * 8] = *(const u16x8*)(vsp + (size_t)(jt * 64 + j) * NKV_ + hk * 128 + c * 8);
  }
  __syncthreads();
  int d = t >> 1, j0 = (t & 1) * 32;
#pragma unroll
  for (int jj = 0; jj < 4; ++jj) {
    u16x8 v;
#pragma unroll
    for (int e = 0; e < 8; ++e) v[e] = tl[j0 + jj * 8 + e][d];
    *(u16x8*)(vspT + ((size_t)hk * 128 + d) * S_ + jt * 64 + j0 + jj * 8) = v;
  }
}

// ---------------- main attention ----------------
#define SPAD_ 66
__global__ __launch_bounds__(256) void attn_kernel(const ushort_t* __restrict__ qbp,
                                                   const ushort_t* __restrict__ ksp,
                                                   const ushort_t* __restrict__ vspT,
                                                   const float* __restrict__ ebias,
                                                   ushort_t* __restrict__ ob16) {
  __shared__ ushort_t k_lds[64 * 128];
  __shared__ ushort_t vT_lds[128 * 64];
  __shared__ float s_lds[4][16][SPAD_];
  const int b = blockIdx.x;
  const int xcd = b & 7;
  const int idx = b >> 3;
  const int h = xcd * 4 + (idx >> 4);
  const int p = idx & 15;
  const int hk = h >> 2;
  const int t = threadIdx.x;
  const int w = t >> 6, lane = t & 63;
  const int lc = lane & 15, lg = lane >> 4;

  const ushort_t* kbase = ksp + hk * D_;
  const ushort_t* vbase = vspT + (size_t)hk * D_ * S_;

  for (int strip = 0; strip < 2; ++strip) {
    const int qb = (strip == 0) ? p : 31 - p;
    const int q0 = qb * 64 + w * 16;
    s16x8 qfrag[4];
#pragma unroll
    for (int db = 0; db < 4; ++db)
      qfrag[db] = *(const s16x8*)(qbp + (size_t)(q0 + lc) * NQ_ + h * D_ + db * 32 + lg * 8);

    f32x4 o[8];
#pragma unroll
    for (int n = 0; n < 8; ++n) o[n] = 0.f;
    float mr[4] = {-INFINITY, -INFINITY, -INFINITY, -INFINITY};
    float lr[4] = {0.f, 0.f, 0.f, 0.f};

    const int ntj = qb + 1;
    for (int tj = 0; tj < ntj; ++tj) {
      const int j0 = tj * 64;
      __syncthreads();
#pragma unroll
      for (int i = 0; i < 4; ++i) {
        int slot = i * 256 + w * 64 + lane;
        int row = slot >> 4, c = slot & 15;
        const ushort_t* gp = kbase + (size_t)(j0 + row) * NKV_ + ((c ^ (row & 7)) * 8);
        gload_lds16(gp, &k_lds[(i * 256 + w * 64) * 8]);
      }
#pragma unroll
      for (int i = 0; i < 4; ++i) {
        int slot = i * 256 + w * 64 + lane;
        int d = slot >> 3, c = slot & 7;
        const ushort_t* gp = vbase + (size_t)d * S_ + j0 + ((c ^ (d & 7)) * 8);
        gload_lds16(gp, &vT_lds[(i * 256 + w * 64) * 8]);
      }
      __syncthreads();

      f32x4 sfr[4];
#pragma unroll
      for (int js = 0; js < 4; ++js) sfr[js] = 0.f;
#pragma unroll
      for (int js = 0; js < 4; ++js) {
        int row = js * 16 + lc;
#pragma unroll
        for (int db = 0; db < 4; ++db) {
          s16x8 kf = *(const s16x8*)&k_lds[row * 128 + (((db * 4 + lg) ^ (lc & 7)) * 8)];
          sfr[js] = __builtin_amdgcn_mfma_f32_16x16x32_bf16(qfrag[db], kf, sfr[js], 0, 0, 0);
        }
      }
      float eb[4];
#pragma unroll
      for (int js = 0; js < 4; ++js) eb[js] = ebias[hk * S_ + j0 + js * 16 + lc];

      const bool diag = (tj == qb);
      float sclv[4];
#pragma unroll
      for (int r = 0; r < 4; ++r) {
        float sv[4];
#pragma unroll
        for (int js = 0; js < 4; ++js) sv[js] = sfr[js][r] * SCALE_ + eb[js];
        if (diag) {
          int qrow = w * 16 + lg * 4 + r;
#pragma unroll
          for (int js = 0; js < 4; ++js)
            if (js * 16 + lc > qrow) sv[js] = -INFINITY;
        }
        float tm = fmaxf(fmaxf(sv[0], sv[1]), fmaxf(sv[2], sv[3]));
#pragma unroll
        for (int off = 1; off < 16; off <<= 1) tm = fmaxf(tm, __shfl_xor(tm, off, 64));
        float mnew = fmaxf(mr[r], tm);
        float scl = __expf(mr[r] - mnew);
        float ps = 0.f;
#pragma unroll
        for (int js = 0; js < 4; ++js) {
          float e = __expf(sv[js] - mnew);
          s_lds[w][lg * 4 + r][js * 16 + lc] = e;
          ps += e;
        }
#pragma unroll
        for (int off = 1; off < 16; off <<= 1) ps += __shfl_xor(ps, off, 64);
        lr[r] = lr[r] * scl + ps;
        mr[r] = mnew;
        sclv[r] = scl;
      }
#pragma unroll
      for (int n = 0; n < 8; ++n) {
        f32x4 ov = o[n];
#pragma unroll
        for (int r = 0; r < 4; ++r) ov[r] *= sclv[r];
        o[n] = ov;
      }
      asm volatile("s_waitcnt lgkmcnt(0)" ::: "memory");
      s16x8 pa[2];
#pragma unroll
      for (int ks = 0; ks < 2; ++ks) {
        float pv[8];
        *(f32x4*)&pv[0] = *(const f32x4*)&s_lds[w][lc][ks * 32 + lg * 8];
        *(f32x4*)&pv[4] = *(const f32x4*)&s_lds[w][lc][ks * 32 + lg * 8 + 4];
        s16x8 pk;
#pragma unroll
        for (int e = 0; e < 8; ++e) pk[e] = (short)f2bf(pv[e]);
        pa[ks] = pk;
      }
#pragma unroll
      for (int n = 0; n < 8; ++n) {
        int d = n * 16 + lc;
#pragma unroll
        for (int ks = 0; ks < 2; ++ks) {
          s16x8 vf = *(const s16x8*)&vT_lds[d * 64 + (((ks * 4 + lg) ^ (lc & 7)) * 8)];
          o[n] = __builtin_amdgcn_mfma_f32_16x16x32_bf16(pa[ks], vf, o[n], 0, 0, 0);
        }
      }
    }
#pragma unroll
    for (int r = 0; r < 4; ++r) {
      float rinv = 1.0f / lr[r];
      int row = q0 + lg * 4 + r;
#pragma unroll
      for (int n = 0; n < 8; ++n)
        ob16[(size_t)row * NQ_ + h * D_ + n * 16 + lc] = f2bf(o[n][r] * rinv);
    }
  }
}

// ---------------- launcher ----------------
extern "C" void kernel_launch(void* const* d_in, const int* in_sizes, int n_in,
                              void* d_out, int out_size, void* d_ws, size_t ws_size,
                              hipStream_t stream) {
  (void)in_sizes; (void)n_in; (void)out_size; (void)ws_size;
  const float* hid = (const float*)d_in[0];
  const float* wq  = (const float*)d_in[1];
  const float* wk  = (const float*)d_in[2];
  const float* wv  = (const float*)d_in[3];
  const float* wo  = (const float*)d_in[4];
  float* out = (float*)d_out;
  char* ws = (char*)d_ws;
  const size_t MB = 1ull << 20;

  // Overlay map (phase-ordered; intervals checked against launch order):
  ushort_t* h0     = (ushort_t*)(ws + 0 * MB);     // A -> C
  ushort_t* h1     = (ushort_t*)(ws + 16 * MB);    // A -> B
  ushort_t* h2     = (ushort_t*)(ws + 32 * MB);    // A -> B
  ushort_t* wq0T   = (ushort_t*)(ws + 48 * MB);    // A -> C
  ushort_t* wq1T   = (ushort_t*)(ws + 80 * MB);    // A -> D
  ushort_t* wq2T   = (ushort_t*)(ws + 112 * MB);   // A -> D
  ushort_t* wkv0T  = (ushort_t*)(ws + 144 * MB);   // A -> B
  ushort_t* wkv1T  = (ushort_t*)(ws + 160 * MB);   // A -> B
  ushort_t* wkv2T  = (ushort_t*)(ws + 176 * MB);   // A -> B
  float*    qpart  = (float*)(ws + 192 * MB);      // D (16 MB)
  float*    qobs   = (float*)(ws + 208 * MB);      // D -> G (2 MB)
  float*    kvf    = (float*)(ws + 210 * MB);      // B -> I (16 MB)
  float*    kvp    = (float*)(ws + 80 * MB);       // B only (48 MB over dead wq1T/wq2T)
  float*    qf     = (float*)(ws + 80 * MB);       // C -> F (over dead kvp0/1)
  ushort_t* qb16   = (ushort_t*)(ws + 112 * MB);   // F -> I (over dead kvp2)
  float*    s_obs  = (float*)(ws + 0 * MB);        // G (32 MB over dead h0/h1)
  ushort_t* woT    = (ushort_t*)(ws + 144 * MB);   // E -> I (over dead wkv0T/1T)
  ushort_t* ksp    = (ushort_t*)(ws + 176 * MB);   // I (over dead wkv2T)
  ushort_t* vsp    = (ushort_t*)(ws + 180 * MB);
  ushort_t* vspT   = (ushort_t*)(ws + 184 * MB);
  ushort_t* ob16   = (ushort_t*)(ws + 188 * MB);   // I (over dead qpart)
  ushort_t* qo0    = (ushort_t*)(ws + 32 * MB);    // G (over dead h2)
  ushort_t* qo1    = (ushort_t*)(ws + 33 * MB);
  ushort_t* qo2    = (ushort_t*)(ws + 34 * MB);
  ushort_t* kb0    = (ushort_t*)(ws + 35 * MB);
  ushort_t* kb1    = (ushort_t*)(ws + 39 * MB);
  ushort_t* kb2    = (ushort_t*)(ws + 43 * MB);
  char*     misc   = ws + 226 * MB;
  float*    impv   = (float*)(misc + 0);
  float*    eb     = (float*)(misc + 64 * 1024);
  float*    invf   = (float*)(misc + 128 * 1024);
  float*    thr    = (float*)(misc + 132 * 1024);
  float*    mxbuf  = (float*)(misc + 160 * 1024);
  float*    dinvb  = (float*)(misc + 192 * 1024);
  float*    part   = (float*)(misc + 256 * 1024);  // 512 KB

  // A) splits
  split3_kernel<<<(S_ * HID_ / 4 + 255) / 256, 256, 0, stream>>>(hid, h0, h1, h2, S_ * HID_ / 4);
  splitT_kernel<<<dim3(NQ_ / 64, HID_ / 64), 256, 0, stream>>>(wq, NQ_, wq0T, wq1T, wq2T);
  splitT_kernel<<<dim3(NKV_ / 64, HID_ / 64), 256, 0, stream>>>(wk, NKV_, wkv0T, wkv1T, wkv2T);
  splitT_kernel<<<dim3(NKV_ / 64, HID_ / 64), 256, 0, stream>>>(
      wv, NKV_, wkv0T + (size_t)NKV_ * HID_, wkv1T + (size_t)NKV_ * HID_, wkv2T + (size_t)NKV_ * HID_);

  // D) obs-Q: 6-term virtual-K, z = K-slice; fixed-order reduce
  const size_t obs_off = (size_t)(S_ - OBS_) * HID_;
  {
    TermPtrs P;
    P.a[0] = h0 + obs_off; P.b[0] = wq0T;
    P.a[1] = h0 + obs_off; P.b[1] = wq1T;
    P.a[2] = h1 + obs_off; P.b[2] = wq0T;
    P.a[3] = h1 + obs_off; P.b[3] = wq1T;
    P.a[4] = h0 + obs_off; P.b[4] = wq2T;
    P.a[5] = h2 + obs_off; P.b[5] = wq0T;
    gemm6k<<<dim3(NQ_ / 128, 1, 8), 256, 0, stream>>>(P, qpart, NQ_);
  }
  reduce8_kernel<<<(OBS_ * NQ_ + 255) / 256, 256, 0, stream>>>(qpart, qobs, OBS_ * NQ_);

  // B) K|V: 6-term virtual-K, 2 terms per z (z=3 split-K) + reduce3
  {
    TermPtrs P;
    P.a[0] = h0; P.b[0] = wkv0T;
    P.a[1] = h0; P.b[1] = wkv1T;
    P.a[2] = h1; P.b[2] = wkv0T;
    P.a[3] = h1; P.b[3] = wkv1T;
    P.a[4] = h0; P.b[4] = wkv2T;
    P.a[5] = h2; P.b[5] = wkv0T;
    gemm6<2><<<dim3(KLD_ / 128, S_ / 128, 3), 256, 0, stream>>>(P, kvp, S_, KLD_, HID_);
  }
  reduce3_kernel<<<(S_ * KLD_ / 4 + 255) / 256, 256, 0, stream>>>(kvp, kvf, S_ * KLD_ / 4);

  // C) Q main GEMM (single-term bf16)
  {
    TermPtrs P;
    for (int i = 0; i < 6; ++i) { P.a[i] = h0; P.b[i] = wq0T; }
    gemm6<1><<<dim3(NQ_ / 128, S_ / 128, 1), 256, 0, stream>>>(P, qf, S_, NQ_, HID_);
  }

  // E) wo transpose+cast
  splitT_kernel<<<dim3(HID_ / 64, HID_ / 64), 256, 0, stream>>>(wo, HID_, woT, nullptr, nullptr);

  // F) RoPE
  freq_kernel<<<1, 64, 0, stream>>>(invf);
  rope_kernel<<<(S_ * HQ_ * 64 + 255) / 256, 256, 0, stream>>>(qf, qb16, invf, HQ_, NQ_, 0, S_ * HQ_ * 64);
  rope_kernel<<<(S_ * HKV_ * 64 + 255) / 256, 256, 0, stream>>>(kvf, nullptr, invf, HKV_, KLD_, 0, S_ * HKV_ * 64);
  rope_kernel<<<(OBS_ * HQ_ * 64 + 255) / 256, 256, 0, stream>>>(qobs, nullptr, invf, HQ_, NQ_, S_ - OBS_, OBS_ * HQ_ * 64);

  // G) obs importance: splits + 6-term per-head GEMM + reductions
  splitq_obs<<<(OBS_ * NQ_ / 4 + 255) / 256, 256, 0, stream>>>(qobs, qo0, qo1, qo2);
  splitk_obs<<<(S_ * NKV_ / 4 + 255) / 256, 256, 0, stream>>>(kvf, kb0, kb1, kb2);
  {
    TermPtrs P;
    P.a[0] = qo0; P.b[0] = kb0;
    P.a[1] = qo0; P.b[1] = kb1;
    P.a[2] = qo1; P.b[2] = kb0;
    P.a[3] = qo1; P.b[3] = kb1;
    P.a[4] = qo0; P.b[4] = kb2;
    P.a[5] = qo2; P.b[5] = kb0;
    gemm6z<<<dim3(16, 4, 8), 256, 0, stream>>>(P, s_obs);
  }
  rowstat_kernel<<<1024, 256, 0, stream>>>(s_obs, mxbuf, dinvb);
  colsum_part<<<dim3(8, 8, 8), 256, 0, stream>>>(s_obs, mxbuf, dinvb, part);
  colsum_fin<<<64, 256, 0, stream>>>(part, impv);

  // H) quantile thresholds (single block, 4 radix passes internal)
  radix_all<<<1, 1024, 0, stream>>>(impv, thr);

  // I) sparsify + V-transpose + attention + out projection
  sparsify_kernel<<<S_ * HKV_, 128, 0, stream>>>(kvf, impv, thr, ksp, vsp, eb);
  vtrans_kernel<<<dim3(S_ / 64, HKV_), 256, 0, stream>>>(vsp, vspT);
  attn_kernel<<<512, 256, 0, stream>>>(qb16, ksp, vspT, eb, ob16);
  {
    TermPtrs P;
    for (int i = 0; i < 6; ++i) { P.a[i] = ob16; P.b[i] = woT; }
    gemm6<1><<<dim3(HID_ / 128, S_ / 128, 1), 256, 0, stream>>>(P, out, S_, HID_, HID_);
  }
}